// Round 4
// baseline (486.912 us; speedup 1.0000x reference)
//
#include <hip/hip_runtime.h>
#include <hip/hip_bf16.h>
#include <cstdint>

#define N_NODES 10000
#define N_EDGES 160000
#define MPAD    10112   // 79 * 128

typedef __attribute__((ext_vector_type(8))) short short8;
typedef __attribute__((ext_vector_type(4))) float floatx4;

// ---------------- helpers ----------------

__device__ __forceinline__ unsigned short bf16_rn(float f) {
    union { float f; unsigned u; } c{f};
    unsigned r = c.u + 0x7FFF + ((c.u >> 16) & 1);   // round-to-nearest-even
    return (unsigned short)(r >> 16);
}
__device__ __forceinline__ float bf16_to_f(unsigned short h) {
    union { unsigned u; float f; } c{(unsigned)h << 16};
    return c.f;
}
__device__ __forceinline__ unsigned pack_hi2(float a, float b) {
    return (unsigned)bf16_rn(a) | ((unsigned)bf16_rn(b) << 16);
}
__device__ __forceinline__ unsigned pack_lo2(float a, float b) {
    float ra = a - bf16_to_f(bf16_rn(a));
    float rb = b - bf16_to_f(bf16_rn(b));
    return (unsigned)bf16_rn(ra) | ((unsigned)bf16_rn(rb) << 16);
}

__device__ __forceinline__ void gload_lds16(const void* g, void* l) {
    __builtin_amdgcn_global_load_lds(
        (const __attribute__((address_space(1))) unsigned int*)g,
        (__attribute__((address_space(3))) unsigned int*)l, 16, 0, 0);
}

// ---------------- edge preprocessing ----------------

__global__ void deg_kernel(const int* __restrict__ src, const int* __restrict__ dst,
                           const float* __restrict__ ew,
                           float* __restrict__ deg, int* __restrict__ cnt) {
    int e = blockIdx.x * blockDim.x + threadIdx.x;
    if (e >= N_EDGES) return;
    atomicAdd(&deg[src[e]], ew[e]);
    atomicAdd(&cnt[dst[e]], 1);
}

// block 0: exclusive scan cnt -> rowptr ; blocks 1..39: dis = rsqrt(deg)
__global__ __launch_bounds__(1024) void dis_scan_kernel(const float* __restrict__ deg,
                                                        const int* __restrict__ cnt,
                                                        float* __restrict__ dis,
                                                        int* __restrict__ rowptr) {
    const int t = threadIdx.x;
    if (blockIdx.x != 0) {
        int n = (blockIdx.x - 1) * 1024 + t;
        if (n < N_NODES) {
            float d = deg[n];
            dis[n] = d > 0.f ? rsqrtf(d) : 0.f;
        }
        return;
    }
    __shared__ int wsum[16];
    const int lane = t & 63, wid = t >> 6;
    int carry = 0;
    for (int base = 0; base < N_NODES; base += 1024) {
        int i = base + t;
        int v = (i < N_NODES) ? cnt[i] : 0;
        int s = v;
        #pragma unroll
        for (int off = 1; off < 64; off <<= 1) {
            int u = __shfl_up(s, off);
            if (lane >= off) s += u;
        }
        if (lane == 63) wsum[wid] = s;
        __syncthreads();
        int woff = 0, tot = 0;
        for (int ww = 0; ww < 16; ++ww) {
            int xv = wsum[ww];
            if (ww < wid) woff += xv;
            tot += xv;
        }
        if (i < N_NODES) rowptr[i + 1] = carry + woff + s;
        carry += tot;
        __syncthreads();
    }
    if (t == 0) rowptr[0] = 0;
}

__global__ void fill_kernel(const int* __restrict__ src, const int* __restrict__ dst,
                            const float* __restrict__ ew, const float* __restrict__ dis,
                            const int* __restrict__ rowptr, int* __restrict__ fill,
                            int* __restrict__ csr_src, float* __restrict__ csr_w) {
    int e = blockIdx.x * blockDim.x + threadIdx.x;
    if (e >= N_EDGES) return;
    int s = src[e], d = dst[e];
    int pos = rowptr[d] + atomicAdd(&fill[d], 1);
    csr_src[pos] = s;
    csr_w[pos] = -dis[s] * ew[e] * dis[d];
}

// ---------------- conversions (all fused into one dispatch) ----------------
// A' layout: [Mpad][2K] bf16, cols [0,K)=hi, [K,2K)=lo

__device__ __forceinline__ void cvt_x_body(int bid, const float* __restrict__ x,
                                           unsigned short* __restrict__ Ap,
                                           int M, int K) {
    int i = bid * 256 + threadIdx.x;   // float4 index
    int kq4 = K >> 2;
    if (i >= M * kq4) return;
    int m = i / kq4, kq = i - m * kq4;
    float4 v = ((const float4*)x)[i];
    uint2 hi, lo;
    hi.x = pack_hi2(v.x, v.y); hi.y = pack_hi2(v.z, v.w);
    lo.x = pack_lo2(v.x, v.y); lo.y = pack_lo2(v.z, v.w);
    size_t row = (size_t)m * 2 * K;
    *(uint2*)&Ap[row + kq * 4]     = hi;
    *(uint2*)&Ap[row + K + kq * 4] = lo;
}

__device__ __forceinline__ void cvt_w_body(int bid, const float* __restrict__ W,
                                           unsigned short* __restrict__ BpT,
                                           int K, int N) {
    int i = bid * 256 + threadIdx.x;
    if (i >= N * (K >> 3)) return;
    int n = i % N, k8 = i / N;
    float v[8];
    #pragma unroll
    for (int j = 0; j < 8; ++j) v[j] = W[(size_t)(k8 * 8 + j) * N + n];
    uint4 hi, lo;
    hi.x = pack_hi2(v[0], v[1]); hi.y = pack_hi2(v[2], v[3]);
    hi.z = pack_hi2(v[4], v[5]); hi.w = pack_hi2(v[6], v[7]);
    lo.x = pack_lo2(v[0], v[1]); lo.y = pack_lo2(v[2], v[3]);
    lo.z = pack_lo2(v[4], v[5]); lo.w = pack_lo2(v[6], v[7]);
    size_t row = (size_t)n * 2 * K;
    *(uint4*)&BpT[row + k8 * 8]     = hi;
    *(uint4*)&BpT[row + K + k8 * 8] = lo;
}

__global__ __launch_bounds__(256) void cvt_all_kernel(const float* __restrict__ x,
                                                      unsigned short* __restrict__ A1,
                                                      const float* __restrict__ W1,
                                                      unsigned short* __restrict__ B1T,
                                                      const float* __restrict__ W2a,
                                                      const float* __restrict__ W2b,
                                                      unsigned short* __restrict__ B2T,
                                                      const float* __restrict__ W3a,
                                                      const float* __restrict__ W3b,
                                                      const float* __restrict__ W3c,
                                                      unsigned short* __restrict__ B3T) {
    int b = blockIdx.x;
    if (b < 7500)       cvt_x_body(b, x, A1, N_NODES, 768);
    else if (b < 7692)  cvt_w_body(b - 7500, W1, B1T, 768, 512);
    else if (b < 7756)  cvt_w_body(b - 7692, W2a, B2T, 512, 256);
    else if (b < 7820)  cvt_w_body(b - 7756, W2b, B2T + (size_t)256 * 1024, 512, 256);
    else if (b < 7836)  cvt_w_body(b - 7820, W3a, B3T, 256, 128);
    else if (b < 7852)  cvt_w_body(b - 7836, W3b, B3T + (size_t)128 * 512, 256, 128);
    else                cvt_w_body(b - 7852, W3c, B3T + (size_t)256 * 512, 256, 128);
}

// fused: sc/sh computed inline from sums; v = relu(G*sc + sh); split hi/lo
__global__ __launch_bounds__(256) void bn_relu_cvt_kernel(const float* __restrict__ G,
                                                          const float* __restrict__ sums,
                                                          const float* __restrict__ g,
                                                          const float* __restrict__ be,
                                                          unsigned short* __restrict__ Ap,
                                                          int M, int F) {
    int i = blockIdx.x * 256 + threadIdx.x;
    int fq4 = F >> 2;
    if (i >= M * fq4) return;
    int m = i / fq4, kq = i - m * fq4;
    const float invM = 1.0f / (float)N_NODES;
    float4 S = ((const float4*)sums)[kq];
    float4 Q = ((const float4*)(sums + F))[kq];
    float4 gg = ((const float4*)g)[kq];
    float4 bb = ((const float4*)be)[kq];
    float4 mu, sc, sh;
    mu.x = S.x * invM; mu.y = S.y * invM; mu.z = S.z * invM; mu.w = S.w * invM;
    sc.x = gg.x * rsqrtf(Q.x * invM - mu.x * mu.x + 1e-5f);
    sc.y = gg.y * rsqrtf(Q.y * invM - mu.y * mu.y + 1e-5f);
    sc.z = gg.z * rsqrtf(Q.z * invM - mu.z * mu.z + 1e-5f);
    sc.w = gg.w * rsqrtf(Q.w * invM - mu.w * mu.w + 1e-5f);
    sh.x = bb.x - mu.x * sc.x; sh.y = bb.y - mu.y * sc.y;
    sh.z = bb.z - mu.z * sc.z; sh.w = bb.w - mu.w * sc.w;
    float4 v = ((const float4*)G)[i];
    v.x = fmaxf(v.x * sc.x + sh.x, 0.f);
    v.y = fmaxf(v.y * sc.y + sh.y, 0.f);
    v.z = fmaxf(v.z * sc.z + sh.z, 0.f);
    v.w = fmaxf(v.w * sc.w + sh.w, 0.f);
    uint2 hi, lo;
    hi.x = pack_hi2(v.x, v.y); hi.y = pack_hi2(v.z, v.w);
    lo.x = pack_lo2(v.x, v.y); lo.y = pack_lo2(v.z, v.w);
    size_t row = (size_t)m * 2 * F;
    *(uint2*)&Ap[row + kq * 4]     = hi;
    *(uint2*)&Ap[row + F + kq * 4] = lo;
}

// ---------------- bf16x3 MFMA GEMM, k-chunk-major LDS (conflict-free) ----------------
// C(MxNc) = A * B over K'=3*Ksub with block map A:[hi,lo,hi], B:[hi,hi,lo]
// LDS layout: idx16 = kq*128 + row  (kq = 16B k-chunk 0..3, row 0..127)
// -> wave reads (16 lanes x 16B contiguous) are bank-conflict-free; staging
//    keeps LDS dest linear (global_load_lds requirement) and re-derives the
//    per-lane GLOBAL address instead.

__global__ __launch_bounds__(256, 2) void mfma_gemm_kernel(
        const unsigned short* __restrict__ Ap,    // Mpad x 2*Ksub
        const unsigned short* __restrict__ BpT,   // Nc x 2*Ksub
        float* __restrict__ C,                    // M x Nc
        int M, int Ksub, int Nc, int ncb,
        float* __restrict__ sums) {               // if non-null: fold BN stats
    constexpr int BK = 32;
    __shared__ unsigned short As[128 * BK];
    __shared__ unsigned short Bs[128 * BK];
    const int t = threadIdx.x;
    const int w = t >> 6, l = t & 63;

    // bijective XCD swizzle (m204)
    int nwg = gridDim.x, bid = blockIdx.x;
    int q = nwg >> 3, r = nwg & 7;
    int xcd = bid & 7, idx = bid >> 3;
    int wgid = (xcd < r ? xcd * (q + 1) : r * (q + 1) + (xcd - r) * q) + idx;
    const int row0 = (wgid / ncb) * 128;
    const int col0 = (wgid % ncb) * 128;

    const int lda = 2 * Ksub;
    const int Ktot = 3 * Ksub;
    const int wr = w >> 1, wc = w & 1;      // 2x2 waves, 64x64 wave tile
    const int lr = l & 15, kq = l >> 4;

    floatx4 acc[4][4] = {};

    for (int k0 = 0; k0 < Ktot; k0 += BK) {
        int kA = (k0 < 2 * Ksub) ? k0 : k0 - 2 * Ksub;   // A blocks: hi, lo, hi
        int kB = (k0 < Ksub)     ? k0 : k0 - Ksub;       // B blocks: hi, hi, lo
        #pragma unroll
        for (int i = 0; i < 2; ++i) {
            int u = i * 4 + w;                 // unit 0..7: 1 KiB each
            int srow = ((u & 1) << 6) + l;     // global row this lane fetches
            int skc  = (u >> 1) * 8;           // 16B k-chunk (elements)
            gload_lds16(Ap + (size_t)(row0 + srow) * lda + kA + skc,
                        (char*)As + u * 1024);
            gload_lds16(BpT + (size_t)(col0 + srow) * lda + kB + skc,
                        (char*)Bs + u * 1024);
        }
        __syncthreads();
        short8 af[4], bfr[4];
        #pragma unroll
        for (int m = 0; m < 4; ++m)
            af[m] = *(const short8*)&As[(kq * 128 + wr * 64 + m * 16 + lr) * 8];
        #pragma unroll
        for (int n = 0; n < 4; ++n)
            bfr[n] = *(const short8*)&Bs[(kq * 128 + wc * 64 + n * 16 + lr) * 8];
        #pragma unroll
        for (int m = 0; m < 4; ++m)
            #pragma unroll
            for (int n = 0; n < 4; ++n)
                acc[m][n] = __builtin_amdgcn_mfma_f32_16x16x32_bf16(
                    af[m], bfr[n], acc[m][n], 0, 0, 0);
        __syncthreads();
    }

    // epilogue: C/D layout col=lane&15, row=(lane>>4)*4+j  [m89/m91]
    #pragma unroll
    for (int m = 0; m < 4; ++m) {
        int rb = row0 + wr * 64 + m * 16 + kq * 4;
        #pragma unroll
        for (int j = 0; j < 4; ++j) {
            int rr = rb + j;
            if (rr < M) {
                #pragma unroll
                for (int n = 0; n < 4; ++n)
                    C[(size_t)rr * Nc + col0 + wc * 64 + n * 16 + lr] = acc[m][n][j];
            }
        }
    }

    // optional fused BN column stats (rows >= M contribute ~1e-10: negligible)
    if (sums) {
        float s[4] = {0.f, 0.f, 0.f, 0.f}, qv[4] = {0.f, 0.f, 0.f, 0.f};
        #pragma unroll
        for (int m = 0; m < 4; ++m)
            #pragma unroll
            for (int n = 0; n < 4; ++n)
                #pragma unroll
                for (int j = 0; j < 4; ++j) {
                    float v = acc[m][n][j];
                    s[n] += v; qv[n] += v * v;
                }
        float* red = (float*)As;               // 8 groups x 128 cols x {s,q} = 8 KiB
        int g8 = wr * 4 + kq;
        __syncthreads();
        #pragma unroll
        for (int n = 0; n < 4; ++n) {
            int cl = wc * 64 + n * 16 + lr;
            red[g8 * 256 + cl * 2 + 0] = s[n];
            red[g8 * 256 + cl * 2 + 1] = qv[n];
        }
        __syncthreads();
        float tot = 0.f;
        #pragma unroll
        for (int g = 0; g < 8; ++g) tot += red[g * 256 + t];
        int cl = t >> 1, e = t & 1;
        atomicAdd(&sums[e * 512 + col0 + cl], tot);   // F=512 (layer 1 only)
    }
}

// ---------------- graph propagation ----------------

// fused prop + BN stats: 16 nodes per block, 625 blocks
// out2[n][f] = G2[n][f] + sum_e w * G2[src][256+f]
__global__ __launch_bounds__(256) void prop_l2_stats_kernel(const float* __restrict__ G2,
                                                            const int* __restrict__ rowptr,
                                                            const int* __restrict__ csr_s,
                                                            const float* __restrict__ csr_w,
                                                            float* __restrict__ out2,
                                                            float* __restrict__ sums) {
    const int f = threadIdx.x;
    float s = 0.f, qv = 0.f;
    #pragma unroll 1
    for (int nn = 0; nn < 16; ++nn) {
        const int n = blockIdx.x * 16 + nn;
        const int e1 = rowptr[n + 1];
        float acc = 0.f;
        int e = rowptr[n];
        for (; e + 1 < e1; e += 2) {
            int s0 = csr_s[e], s1 = csr_s[e + 1];
            float w0 = csr_w[e], w1 = csr_w[e + 1];
            acc += w0 * G2[(size_t)s0 * 512 + 256 + f] + w1 * G2[(size_t)s1 * 512 + 256 + f];
        }
        if (e < e1) acc += csr_w[e] * G2[(size_t)csr_s[e] * 512 + 256 + f];
        float v = acc + G2[(size_t)n * 512 + f];
        out2[(size_t)n * 256 + f] = v;
        s += v; qv += v * v;
    }
    atomicAdd(&sums[f], s);
    atomicAdd(&sums[256 + f], qv);
}

// F=128 prop, 2 nodes/block
__global__ __launch_bounds__(256) void prop_f128_kernel(const float* __restrict__ H,
                                                        int ldH, int offH,
                                                        const float* __restrict__ H2,
                                                        float s2,
                                                        const int* __restrict__ rowptr,
                                                        const int* __restrict__ csr_s,
                                                        const float* __restrict__ csr_w,
                                                        float* __restrict__ out) {
    const int n = blockIdx.x * 2 + (threadIdx.x >> 7);
    const int f = threadIdx.x & 127;
    const int e1 = rowptr[n + 1];
    float acc = 0.f;
    if (H2) {
        for (int e = rowptr[n]; e < e1; ++e) {
            int s = csr_s[e];
            acc += csr_w[e] * (H[(size_t)s * ldH + offH + f] + s2 * H2[(size_t)s * 128 + f]);
        }
    } else {
        int e = rowptr[n];
        for (; e + 1 < e1; e += 2) {
            int s0 = csr_s[e], s1 = csr_s[e + 1];
            acc += csr_w[e] * H[(size_t)s0 * ldH + offH + f]
                 + csr_w[e + 1] * H[(size_t)s1 * ldH + offH + f];
        }
        if (e < e1) acc += csr_w[e] * H[(size_t)csr_s[e] * ldH + offH + f];
    }
    out[(size_t)n * 128 + f] = acc;
}

// out3 = G3[:,0:128] - G3[:,256:384] + U ; write F and accumulate BN stats
__global__ __launch_bounds__(128) void combine3_stats_kernel(const float* __restrict__ G3,
                                                             const float* __restrict__ U,
                                                             float* __restrict__ Fbuf,
                                                             float* __restrict__ sums) {
    const int t = threadIdx.x;
    int r0 = blockIdx.x * 80, r1 = min(r0 + 80, N_NODES);
    float s = 0.f, q = 0.f;
    for (int r = r0; r < r1; ++r) {
        float v = G3[(size_t)r * 384 + t] - G3[(size_t)r * 384 + 256 + t]
                + U[(size_t)r * 128 + t];
        Fbuf[(size_t)r * 128 + t] = v;
        s += v; q += v * v;
    }
    atomicAdd(&sums[t], s);
    atomicAdd(&sums[128 + t], q);
}

// ---------------- fused BN3 (inline coeffs) + FC(128->6) + log_softmax ----------------

__global__ __launch_bounds__(256) void final_kernel(const float* __restrict__ h,
                                                    const float* __restrict__ sums,
                                                    const float* __restrict__ g3,
                                                    const float* __restrict__ be3,
                                                    const float* __restrict__ fcW,
                                                    const float* __restrict__ fcb,
                                                    float* __restrict__ out) {
    const int t = threadIdx.x, lane = t & 63, wid = t >> 6;
    const int r = blockIdx.x * 4 + wid;
    if (r >= N_NODES) return;
    const float invM = 1.0f / (float)N_NODES;
    float v[6] = {0.f, 0.f, 0.f, 0.f, 0.f, 0.f};
    #pragma unroll
    for (int kk = 0; kk < 2; ++kk) {
        int k = lane + kk * 64;
        float mu = sums[k] * invM;
        float sc = g3[k] * rsqrtf(sums[128 + k] * invM - mu * mu + 1e-5f);
        float sh = be3[k] - mu * sc;
        float x = h[(size_t)r * 128 + k] * sc + sh;
        #pragma unroll
        for (int j = 0; j < 6; ++j) v[j] += x * fcW[k * 6 + j];
    }
    #pragma unroll
    for (int j = 0; j < 6; ++j)
        #pragma unroll
        for (int off = 32; off > 0; off >>= 1) v[j] += __shfl_down(v[j], off);
    if (lane == 0) {
        #pragma unroll
        for (int j = 0; j < 6; ++j) v[j] += fcb[j];
        float m = v[0];
        #pragma unroll
        for (int j = 1; j < 6; ++j) m = fmaxf(m, v[j]);
        float s = 0.f;
        #pragma unroll
        for (int j = 0; j < 6; ++j) s += expf(v[j] - m);
        float l = m + logf(s);
        #pragma unroll
        for (int j = 0; j < 6; ++j) out[r * 6 + j] = v[j] - l;
    }
}

// ---------------- launch ----------------

extern "C" void kernel_launch(void* const* d_in, const int* in_sizes, int n_in,
                              void* d_out, int out_size, void* d_ws, size_t ws_size,
                              hipStream_t stream) {
    (void)in_sizes; (void)n_in; (void)out_size; (void)ws_size;
    const float* x   = (const float*)d_in[0];
    const int*   ei  = (const int*)d_in[1];
    const float* ea  = (const float*)d_in[2];
    const float* W1  = (const float*)d_in[3];
    // b1/b2/b3 (d_in[4],[9],[15]) cancel under training-mode BN
    const float* g1  = (const float*)d_in[5];
    const float* be1 = (const float*)d_in[6];
    const float* W2a = (const float*)d_in[7];
    const float* W2b = (const float*)d_in[8];
    const float* g2  = (const float*)d_in[10];
    const float* be2 = (const float*)d_in[11];
    const float* W3a = (const float*)d_in[12];
    const float* W3b = (const float*)d_in[13];
    const float* W3c = (const float*)d_in[14];
    const float* g3  = (const float*)d_in[16];
    const float* be3 = (const float*)d_in[17];
    const float* fcW = (const float*)d_in[18];
    const float* fcb = (const float*)d_in[19];
    float* out = (float*)d_out;

    const int* src = ei;
    const int* dst = ei + N_EDGES;

    char* w = (char*)d_ws;
    size_t off = 0;
    auto alloc = [&](size_t bytes) -> void* {
        void* p = w + off;
        off += (bytes + 4095) & ~(size_t)4095;
        return p;
    };
    // zeroed region first
    float* deg    = (float*)alloc(N_NODES * 4);
    int*   cnt    = (int*)  alloc(N_NODES * 4);
    int*   fillc  = (int*)  alloc(N_NODES * 4);
    float* sums1  = (float*)alloc(1024 * 4);
    float* sums2  = (float*)alloc(1024 * 4);
    float* sums3  = (float*)alloc(1024 * 4);
    size_t zero_bytes = off;
    float* dis    = (float*)alloc(N_NODES * 4);
    int*   rowptr = (int*)  alloc((N_NODES + 1) * 4);
    int*   csr_s  = (int*)  alloc(N_EDGES * 4);
    float* csr_w  = (float*)alloc(N_EDGES * 4);
    unsigned short* B1T = (unsigned short*)alloc((size_t)512 * 1536 * 2);
    unsigned short* B2T = (unsigned short*)alloc((size_t)512 * 1024 * 2);
    unsigned short* B3T = (unsigned short*)alloc((size_t)384 * 512 * 2);
    // aliased big slots
    unsigned short* slotA = (unsigned short*)alloc((size_t)MPAD * 1536 * 2); // A'1/A'2/A'3
    float* slotG = (float*)alloc((size_t)N_NODES * 512 * 4);                 // G1/G2/G3
    float* slotC = (float*)alloc((size_t)N_NODES * 256 * 4);                 // out2 ; T|U
    float* bufF  = (float*)alloc((size_t)N_NODES * 128 * 4);

    unsigned short* A1 = slotA;
    unsigned short* A2 = slotA;
    unsigned short* A3 = slotA;
    float* G1 = slotG;
    float* G2 = slotG;
    float* G3 = slotG;
    float* out2 = slotC;
    float* bufT = slotC;
    float* bufU = slotC + (size_t)N_NODES * 128;

    hipMemsetAsync(d_ws, 0, zero_bytes, stream);

    // graph preprocessing -> dst-CSR with normalized weights
    deg_kernel<<<N_EDGES / 256, 256, 0, stream>>>(src, dst, ea, deg, cnt);
    dis_scan_kernel<<<40, 1024, 0, stream>>>(deg, cnt, dis, rowptr);
    fill_kernel<<<N_EDGES / 256, 256, 0, stream>>>(src, dst, ea, dis, rowptr, fillc,
                                                   csr_s, csr_w);

    // all fp32->bf16 hi/lo conversions in one dispatch
    cvt_all_kernel<<<7868, 256, 0, stream>>>(x, A1, W1, B1T, W2a, W2b, B2T,
                                             W3a, W3b, W3c, B3T);

    // ---- layer 1: G1 = x @ W1 (bf16x3) + fused BN stats; BN+ReLU+cvt -> A'2 ----
    mfma_gemm_kernel<<<316, 256, 0, stream>>>(A1, B1T, G1, N_NODES, 768, 512, 4, sums1);
    bn_relu_cvt_kernel<<<5000, 256, 0, stream>>>(G1, sums1, g1, be1, A2, N_NODES, 512);

    // ---- layer 2: G2 = h1 @ [W2a|W2b]; out2 = y0 + P y1 (+stats); cvt -> A'3 ----
    mfma_gemm_kernel<<<316, 256, 0, stream>>>(A2, B2T, G2, N_NODES, 512, 512, 4, nullptr);
    prop_l2_stats_kernel<<<625, 256, 0, stream>>>(G2, rowptr, csr_s, csr_w, out2, sums2);
    bn_relu_cvt_kernel<<<2500, 256, 0, stream>>>(out2, sums2, g2, be2, A3, N_NODES, 256);

    // ---- layer 3: G3 = h2 @ [W3a|W3b|W3c] = [f0|g1|g2] ----
    mfma_gemm_kernel<<<237, 256, 0, stream>>>(A3, B3T, G3, N_NODES, 256, 384, 3, nullptr);
    // t = P g2 ; u = P (g1 + 2 t) ; out3 = f0 - g2 + u
    prop_f128_kernel<<<N_NODES / 2, 256, 0, stream>>>(G3, 384, 256, nullptr, 0.f,
                                                      rowptr, csr_s, csr_w, bufT);
    prop_f128_kernel<<<N_NODES / 2, 256, 0, stream>>>(G3, 384, 128, bufT, 2.f,
                                                      rowptr, csr_s, csr_w, bufU);
    combine3_stats_kernel<<<125, 128, 0, stream>>>(G3, bufU, bufF, sums3);

    // ---- BN3 (inline coeffs) + FC + log_softmax fused ----
    final_kernel<<<2500, 256, 0, stream>>>(bufF, sums3, g3, be3, fcW, fcb, out);
}

// Round 5
// 429.734 us; speedup vs baseline: 1.1331x; 1.1331x over previous
//
#include <hip/hip_runtime.h>
#include <hip/hip_bf16.h>
#include <cstdint>

#define N_NODES 10000
#define N_EDGES 160000
#define MPAD    10112   // 79 * 128

typedef __attribute__((ext_vector_type(8))) short short8;
typedef __attribute__((ext_vector_type(4))) float floatx4;
typedef unsigned short us;

// ---------------- helpers ----------------

__device__ __forceinline__ us bf16_rn(float f) {
    union { float f; unsigned u; } c{f};
    unsigned r = c.u + 0x7FFF + ((c.u >> 16) & 1);   // round-to-nearest-even
    return (us)(r >> 16);
}
__device__ __forceinline__ float bf16_to_f(us h) {
    union { unsigned u; float f; } c{(unsigned)h << 16};
    return c.f;
}
__device__ __forceinline__ unsigned pack_hi2(float a, float b) {
    return (unsigned)bf16_rn(a) | ((unsigned)bf16_rn(b) << 16);
}
__device__ __forceinline__ unsigned pack_lo2(float a, float b) {
    float ra = a - bf16_to_f(bf16_rn(a));
    float rb = b - bf16_to_f(bf16_rn(b));
    return (unsigned)bf16_rn(ra) | ((unsigned)bf16_rn(rb) << 16);
}

__device__ __forceinline__ void gload_lds16(const void* g, void* l) {
    __builtin_amdgcn_global_load_lds(
        (const __attribute__((address_space(1))) unsigned int*)g,
        (__attribute__((address_space(3))) unsigned int*)l, 16, 0, 0);
}

// ================= tile-packed bf16 layouts =================
// A_packed: per 128-row panel pa, per 32-k tile kt: 4096 elems laid out as
//   elem((kq*128 + rr)*8 + e)  for k = kt*32 + kq*8 + e, row = pa*128 + rr.
// Width axis is the [hi | lo] concat (2K total): hi tiles kt=0..K/32-1, lo after.
// B_packed: per 64-col panel pb, per 32-k tile: 2048 elems, (kq*64 + c)*8 + e.
// GEMM staging is then a LINEAR 1KiB-per-instruction copy (perfect coalescing)
// and LDS reads are the proven conflict-free k-chunk-major pattern.

// ---------------- edge preprocessing ----------------

__global__ void deg_kernel(const int* __restrict__ src, const int* __restrict__ dst,
                           const float* __restrict__ ew,
                           float* __restrict__ deg, int* __restrict__ cnt) {
    int e = blockIdx.x * blockDim.x + threadIdx.x;
    if (e >= N_EDGES) return;
    atomicAdd(&deg[src[e]], ew[e]);
    atomicAdd(&cnt[dst[e]], 1);
}

// block 0: exclusive scan cnt -> rowptr ; blocks 1..39: dis = rsqrt(deg)
__global__ __launch_bounds__(1024) void dis_scan_kernel(const float* __restrict__ deg,
                                                        const int* __restrict__ cnt,
                                                        float* __restrict__ dis,
                                                        int* __restrict__ rowptr) {
    const int t = threadIdx.x;
    if (blockIdx.x != 0) {
        int n = (blockIdx.x - 1) * 1024 + t;
        if (n < N_NODES) {
            float d = deg[n];
            dis[n] = d > 0.f ? rsqrtf(d) : 0.f;
        }
        return;
    }
    __shared__ int wsum[16];
    const int lane = t & 63, wid = t >> 6;
    int carry = 0;
    for (int base = 0; base < N_NODES; base += 1024) {
        int i = base + t;
        int v = (i < N_NODES) ? cnt[i] : 0;
        int s = v;
        #pragma unroll
        for (int off = 1; off < 64; off <<= 1) {
            int u = __shfl_up(s, off);
            if (lane >= off) s += u;
        }
        if (lane == 63) wsum[wid] = s;
        __syncthreads();
        int woff = 0, tot = 0;
        for (int ww = 0; ww < 16; ++ww) {
            int xv = wsum[ww];
            if (ww < wid) woff += xv;
            tot += xv;
        }
        if (i < N_NODES) rowptr[i + 1] = carry + woff + s;
        carry += tot;
        __syncthreads();
    }
    if (t == 0) rowptr[0] = 0;
}

__global__ void fill_kernel(const int* __restrict__ src, const int* __restrict__ dst,
                            const float* __restrict__ ew, const float* __restrict__ dis,
                            const int* __restrict__ rowptr, int* __restrict__ fill,
                            int* __restrict__ csr_src, float* __restrict__ csr_w) {
    int e = blockIdx.x * blockDim.x + threadIdx.x;
    if (e >= N_EDGES) return;
    int s = src[e], d = dst[e];
    int pos = rowptr[d] + atomicAdd(&fill[d], 1);
    csr_src[pos] = s;
    csr_w[pos] = -dis[s] * ew[e] * dis[d];
}

// ---------------- packed conversions ----------------

// x (M x 768 fp32, row-major) -> A1 packed (width 1536 = hi|lo)
__device__ __forceinline__ void cvt_x_body(int bx, int k16, const float* __restrict__ x,
                                           us* __restrict__ Ap) {
    int m = bx * 256 + threadIdx.x;
    if (m >= N_NODES) return;
    const float4* p = (const float4*)(x + (size_t)m * 768 + k16 * 16);
    float4 v0 = p[0], v1 = p[1], v2 = p[2], v3 = p[3];
    uint4 hi0, hi1, lo0, lo1;
    hi0.x = pack_hi2(v0.x, v0.y); hi0.y = pack_hi2(v0.z, v0.w);
    hi0.z = pack_hi2(v1.x, v1.y); hi0.w = pack_hi2(v1.z, v1.w);
    hi1.x = pack_hi2(v2.x, v2.y); hi1.y = pack_hi2(v2.z, v2.w);
    hi1.z = pack_hi2(v3.x, v3.y); hi1.w = pack_hi2(v3.z, v3.w);
    lo0.x = pack_lo2(v0.x, v0.y); lo0.y = pack_lo2(v0.z, v0.w);
    lo0.z = pack_lo2(v1.x, v1.y); lo0.w = pack_lo2(v1.z, v1.w);
    lo1.x = pack_lo2(v2.x, v2.y); lo1.y = pack_lo2(v2.z, v2.w);
    lo1.z = pack_lo2(v3.x, v3.y); lo1.w = pack_lo2(v3.z, v3.w);
    int pa = m >> 7, rr = m & 127;
    int kt = k16 >> 1, kqb = (k16 & 1) * 2;
    size_t th = ((size_t)pa * 48 + kt) * 4096;        // NKT=48, hi tiles 0..23
    size_t tl = ((size_t)pa * 48 + 24 + kt) * 4096;   // lo tiles 24..47
    *(uint4*)&Ap[th + ((kqb + 0) * 128 + rr) * 8] = hi0;
    *(uint4*)&Ap[th + ((kqb + 1) * 128 + rr) * 8] = hi1;
    *(uint4*)&Ap[tl + ((kqb + 0) * 128 + rr) * 8] = lo0;
    *(uint4*)&Ap[tl + ((kqb + 1) * 128 + rr) * 8] = lo1;
}

// W (K x N fp32 row-major) -> B packed (panels of 64 cols, width 2K)
__device__ __forceinline__ void cvt_w_body(int bx, int k16, const float* __restrict__ W,
                                           us* __restrict__ Bp, int K, int N) {
    int n = bx * 256 + threadIdx.x;
    if (n >= N) return;
    float v[16];
    #pragma unroll
    for (int j = 0; j < 16; ++j) v[j] = W[(size_t)(k16 * 16 + j) * N + n];
    uint4 hi0, hi1, lo0, lo1;
    hi0.x = pack_hi2(v[0], v[1]);  hi0.y = pack_hi2(v[2], v[3]);
    hi0.z = pack_hi2(v[4], v[5]);  hi0.w = pack_hi2(v[6], v[7]);
    hi1.x = pack_hi2(v[8], v[9]);  hi1.y = pack_hi2(v[10], v[11]);
    hi1.z = pack_hi2(v[12], v[13]); hi1.w = pack_hi2(v[14], v[15]);
    lo0.x = pack_lo2(v[0], v[1]);  lo0.y = pack_lo2(v[2], v[3]);
    lo0.z = pack_lo2(v[4], v[5]);  lo0.w = pack_lo2(v[6], v[7]);
    lo1.x = pack_lo2(v[8], v[9]);  lo1.y = pack_lo2(v[10], v[11]);
    lo1.z = pack_lo2(v[12], v[13]); lo1.w = pack_lo2(v[14], v[15]);
    int pb = n >> 6, c = n & 63;
    int NKTB = K >> 4;                       // 2K/32
    int kt = k16 >> 1, kqb = (k16 & 1) * 2;
    size_t th = ((size_t)pb * NKTB + kt) * 2048;
    size_t tl = ((size_t)pb * NKTB + (K >> 5) + kt) * 2048;
    *(uint4*)&Bp[th + ((kqb + 0) * 64 + c) * 8] = hi0;
    *(uint4*)&Bp[th + ((kqb + 1) * 64 + c) * 8] = hi1;
    *(uint4*)&Bp[tl + ((kqb + 0) * 64 + c) * 8] = lo0;
    *(uint4*)&Bp[tl + ((kqb + 1) * 64 + c) * 8] = lo1;
}

__global__ __launch_bounds__(256) void cvt_all_kernel(const float* __restrict__ x,
                                                      us* __restrict__ A1,
                                                      const float* __restrict__ W1,
                                                      us* __restrict__ B1T,
                                                      const float* __restrict__ W2a,
                                                      const float* __restrict__ W2b,
                                                      us* __restrict__ B2T,
                                                      const float* __restrict__ W3a,
                                                      const float* __restrict__ W3b,
                                                      const float* __restrict__ W3c,
                                                      us* __restrict__ B3T) {
    int b = blockIdx.x;
    if (b < 1920) { cvt_x_body(b % 40, b / 40, x, A1); return; }
    b -= 1920;
    if (b < 96)  { cvt_w_body(b & 1, b >> 1, W1, B1T, 768, 512); return; }
    b -= 96;
    if (b < 32)  { cvt_w_body(0, b, W2a, B2T, 512, 256); return; }
    b -= 32;
    if (b < 32)  { cvt_w_body(0, b, W2b, B2T + (size_t)4 * 32 * 2048, 512, 256); return; }
    b -= 32;
    if (b < 16)  { cvt_w_body(0, b, W3a, B3T, 256, 128); return; }
    b -= 16;
    if (b < 16)  { cvt_w_body(0, b, W3b, B3T + (size_t)2 * 16 * 2048, 256, 128); return; }
    b -= 16;
    cvt_w_body(0, b, W3c, B3T + (size_t)4 * 16 * 2048, 256, 128);
}

// fused BN(inline coeffs)+ReLU+cvt -> packed A. grid (40, F/16)
__global__ __launch_bounds__(256) void bn_relu_cvt_kernel(const float* __restrict__ G,
                                                          const float* __restrict__ sums,
                                                          const float* __restrict__ g,
                                                          const float* __restrict__ be,
                                                          us* __restrict__ Ap, int F) {
    const int k16 = blockIdx.y;
    int m = blockIdx.x * 256 + threadIdx.x;
    if (m >= N_NODES) return;
    const float invM = 1.0f / (float)N_NODES;
    float sc[16], sh[16];
    #pragma unroll
    for (int j = 0; j < 16; ++j) {
        int c = k16 * 16 + j;
        float mu = sums[c] * invM;
        float s = g[c] * rsqrtf(sums[F + c] * invM - mu * mu + 1e-5f);
        sc[j] = s;
        sh[j] = be[c] - mu * s;
    }
    const float4* p = (const float4*)(G + (size_t)m * F + k16 * 16);
    float v[16];
    #pragma unroll
    for (int q = 0; q < 4; ++q) {
        float4 t4 = p[q];
        v[q * 4 + 0] = t4.x; v[q * 4 + 1] = t4.y;
        v[q * 4 + 2] = t4.z; v[q * 4 + 3] = t4.w;
    }
    #pragma unroll
    for (int j = 0; j < 16; ++j) v[j] = fmaxf(v[j] * sc[j] + sh[j], 0.f);
    uint4 hi0, hi1, lo0, lo1;
    hi0.x = pack_hi2(v[0], v[1]);  hi0.y = pack_hi2(v[2], v[3]);
    hi0.z = pack_hi2(v[4], v[5]);  hi0.w = pack_hi2(v[6], v[7]);
    hi1.x = pack_hi2(v[8], v[9]);  hi1.y = pack_hi2(v[10], v[11]);
    hi1.z = pack_hi2(v[12], v[13]); hi1.w = pack_hi2(v[14], v[15]);
    lo0.x = pack_lo2(v[0], v[1]);  lo0.y = pack_lo2(v[2], v[3]);
    lo0.z = pack_lo2(v[4], v[5]);  lo0.w = pack_lo2(v[6], v[7]);
    lo1.x = pack_lo2(v[8], v[9]);  lo1.y = pack_lo2(v[10], v[11]);
    lo1.z = pack_lo2(v[12], v[13]); lo1.w = pack_lo2(v[14], v[15]);
    int pa = m >> 7, rr = m & 127;
    int NKT = F >> 4;
    int kt = k16 >> 1, kqb = (k16 & 1) * 2;
    size_t th = ((size_t)pa * NKT + kt) * 4096;
    size_t tl = ((size_t)pa * NKT + (F >> 5) + kt) * 4096;
    *(uint4*)&Ap[th + ((kqb + 0) * 128 + rr) * 8] = hi0;
    *(uint4*)&Ap[th + ((kqb + 1) * 128 + rr) * 8] = hi1;
    *(uint4*)&Ap[tl + ((kqb + 0) * 128 + rr) * 8] = lo0;
    *(uint4*)&Ap[tl + ((kqb + 1) * 128 + rr) * 8] = lo1;
}

// ---------------- bf16x3 MFMA GEMM: 128x64 tile, packed tiles ----------------
// Staging: pure linear copy, each global_load_lds = 1KiB contiguous.
// LDS reads: k-chunk-major, conflict-free (verified round 4).

__global__ __launch_bounds__(256, 4) void mfma_gemm_kernel(
        const us* __restrict__ Ap,     // packed, MPAD rows x 2*Ksub
        const us* __restrict__ BpT,    // packed, Nc cols x 2*Ksub
        float* __restrict__ C,         // M x Nc
        int M, int Ksub, int Nc, int ncb,
        float* __restrict__ sums) {    // if non-null: fold BN stats (F=512)
    __shared__ us As[4096];   // 128 rows x 32 k
    __shared__ us Bs[2048];   // 64 cols x 32 k
    const int t = threadIdx.x;
    const int w = t >> 6, l = t & 63;

    // bijective XCD swizzle (m204)
    int nwg = gridDim.x, bid = blockIdx.x;
    int q = nwg >> 3, r = nwg & 7;
    int xcd = bid & 7, idx = bid >> 3;
    int wgid = (xcd < r ? xcd * (q + 1) : r * (q + 1) + (xcd - r) * q) + idx;
    const int row0 = (wgid / ncb) * 128;
    const int col0 = (wgid % ncb) * 64;

    const int NKTA = Ksub >> 4;   // 2*Ksub/32 tiles along packed width
    const int Ktot = 3 * Ksub;
    const int wr = w >> 1, wc = w & 1;     // 2x2 waves: 64-row x 32-col sub-tiles
    const int lr = l & 15, kq = l >> 4;

    const size_t Abase = (size_t)(row0 >> 7) * NKTA * 4096;
    const size_t Bbase = (size_t)(col0 >> 6) * NKTA * 2048;

    floatx4 acc[4][2] = {};

    for (int k0 = 0; k0 < Ktot; k0 += 32) {
        int kA = (k0 < 2 * Ksub) ? k0 : k0 - 2 * Ksub;   // A blocks: hi, lo, hi
        int kB = (k0 < Ksub)     ? k0 : k0 - Ksub;       // B blocks: hi, hi, lo
        const us* At = Ap + Abase + (size_t)(kA >> 5) * 4096;
        const us* Bt = BpT + Bbase + (size_t)(kB >> 5) * 2048;
        gload_lds16(At + (w * 64 + l) * 8,       (char*)As + w * 1024);
        gload_lds16(At + ((w + 4) * 64 + l) * 8, (char*)As + (w + 4) * 1024);
        gload_lds16(Bt + (w * 64 + l) * 8,       (char*)Bs + w * 1024);
        __syncthreads();
        short8 af[4], bfr[2];
        #pragma unroll
        for (int m = 0; m < 4; ++m)
            af[m] = *(const short8*)&As[(kq * 128 + wr * 64 + m * 16 + lr) * 8];
        #pragma unroll
        for (int n = 0; n < 2; ++n)
            bfr[n] = *(const short8*)&Bs[(kq * 64 + wc * 32 + n * 16 + lr) * 8];
        #pragma unroll
        for (int m = 0; m < 4; ++m)
            #pragma unroll
            for (int n = 0; n < 2; ++n)
                acc[m][n] = __builtin_amdgcn_mfma_f32_16x16x32_bf16(
                    af[m], bfr[n], acc[m][n], 0, 0, 0);
        __syncthreads();
    }

    // C/D layout: col=lane&15, row=(lane>>4)*4+j  [m89/m91]
    #pragma unroll
    for (int m = 0; m < 4; ++m) {
        int rb = row0 + wr * 64 + m * 16 + kq * 4;
        #pragma unroll
        for (int j = 0; j < 4; ++j) {
            int rr = rb + j;
            if (rr < M) {
                #pragma unroll
                for (int n = 0; n < 2; ++n)
                    C[(size_t)rr * Nc + col0 + wc * 32 + n * 16 + lr] = acc[m][n][j];
            }
        }
    }

    // optional fused BN column stats (padding rows contribute ~1e-25: negligible)
    if (sums) {
        float s[2] = {0.f, 0.f}, qv[2] = {0.f, 0.f};
        #pragma unroll
        for (int m = 0; m < 4; ++m)
            #pragma unroll
            for (int n = 0; n < 2; ++n)
                #pragma unroll
                for (int j = 0; j < 4; ++j) {
                    float v = acc[m][n][j];
                    s[n] += v; qv[n] += v * v;
                }
        float* red = (float*)As;            // 8 groups x 64 cols x {s,q} = 4 KiB
        int g8 = wr * 4 + kq;
        #pragma unroll
        for (int n = 0; n < 2; ++n) {
            int c = wc * 32 + n * 16 + lr;
            red[g8 * 128 + c * 2 + 0] = s[n];
            red[g8 * 128 + c * 2 + 1] = qv[n];
        }
        __syncthreads();
        if (t < 128) {
            float tot = 0.f;
            #pragma unroll
            for (int g = 0; g < 8; ++g) tot += red[g * 128 + t];
            int c = t >> 1, e = t & 1;
            atomicAdd(&sums[e * 512 + col0 + c], tot);
        }
    }
}

// ---------------- graph propagation ----------------

// fused prop + BN stats: 16 nodes per block, 625 blocks
__global__ __launch_bounds__(256) void prop_l2_stats_kernel(const float* __restrict__ G2,
                                                            const int* __restrict__ rowptr,
                                                            const int* __restrict__ csr_s,
                                                            const float* __restrict__ csr_w,
                                                            float* __restrict__ out2,
                                                            float* __restrict__ sums) {
    const int f = threadIdx.x;
    float s = 0.f, qv = 0.f;
    #pragma unroll 1
    for (int nn = 0; nn < 16; ++nn) {
        const int n = blockIdx.x * 16 + nn;
        const int e1 = rowptr[n + 1];
        float acc = 0.f;
        int e = rowptr[n];
        for (; e + 1 < e1; e += 2) {
            int s0 = csr_s[e], s1 = csr_s[e + 1];
            float w0 = csr_w[e], w1 = csr_w[e + 1];
            acc += w0 * G2[(size_t)s0 * 512 + 256 + f] + w1 * G2[(size_t)s1 * 512 + 256 + f];
        }
        if (e < e1) acc += csr_w[e] * G2[(size_t)csr_s[e] * 512 + 256 + f];
        float v = acc + G2[(size_t)n * 512 + f];
        out2[(size_t)n * 256 + f] = v;
        s += v; qv += v * v;
    }
    atomicAdd(&sums[f], s);
    atomicAdd(&sums[256 + f], qv);
}

// F=128 prop, 2 nodes/block
__global__ __launch_bounds__(256) void prop_f128_kernel(const float* __restrict__ H,
                                                        int ldH, int offH,
                                                        const float* __restrict__ H2,
                                                        float s2,
                                                        const int* __restrict__ rowptr,
                                                        const int* __restrict__ csr_s,
                                                        const float* __restrict__ csr_w,
                                                        float* __restrict__ out) {
    const int n = blockIdx.x * 2 + (threadIdx.x >> 7);
    const int f = threadIdx.x & 127;
    const int e1 = rowptr[n + 1];
    float acc = 0.f;
    if (H2) {
        for (int e = rowptr[n]; e < e1; ++e) {
            int s = csr_s[e];
            acc += csr_w[e] * (H[(size_t)s * ldH + offH + f] + s2 * H2[(size_t)s * 128 + f]);
        }
    } else {
        int e = rowptr[n];
        for (; e + 1 < e1; e += 2) {
            int s0 = csr_s[e], s1 = csr_s[e + 1];
            acc += csr_w[e] * H[(size_t)s0 * ldH + offH + f]
                 + csr_w[e + 1] * H[(size_t)s1 * ldH + offH + f];
        }
        if (e < e1) acc += csr_w[e] * H[(size_t)csr_s[e] * ldH + offH + f];
    }
    out[(size_t)n * 128 + f] = acc;
}

// out3 = G3[:,0:128] - G3[:,256:384] + U ; write F and accumulate BN stats
__global__ __launch_bounds__(128) void combine3_stats_kernel(const float* __restrict__ G3,
                                                             const float* __restrict__ U,
                                                             float* __restrict__ Fbuf,
                                                             float* __restrict__ sums) {
    const int t = threadIdx.x;
    int r0 = blockIdx.x * 80, r1 = min(r0 + 80, N_NODES);
    float s = 0.f, q = 0.f;
    for (int r = r0; r < r1; ++r) {
        float v = G3[(size_t)r * 384 + t] - G3[(size_t)r * 384 + 256 + t]
                + U[(size_t)r * 128 + t];
        Fbuf[(size_t)r * 128 + t] = v;
        s += v; q += v * v;
    }
    atomicAdd(&sums[t], s);
    atomicAdd(&sums[128 + t], q);
}

// ---------------- fused BN3 (inline coeffs) + FC(128->6) + log_softmax ----------------

__global__ __launch_bounds__(256) void final_kernel(const float* __restrict__ h,
                                                    const float* __restrict__ sums,
                                                    const float* __restrict__ g3,
                                                    const float* __restrict__ be3,
                                                    const float* __restrict__ fcW,
                                                    const float* __restrict__ fcb,
                                                    float* __restrict__ out) {
    const int t = threadIdx.x, lane = t & 63, wid = t >> 6;
    const int r = blockIdx.x * 4 + wid;
    if (r >= N_NODES) return;
    const float invM = 1.0f / (float)N_NODES;
    float v[6] = {0.f, 0.f, 0.f, 0.f, 0.f, 0.f};
    #pragma unroll
    for (int kk = 0; kk < 2; ++kk) {
        int k = lane + kk * 64;
        float mu = sums[k] * invM;
        float sc = g3[k] * rsqrtf(sums[128 + k] * invM - mu * mu + 1e-5f);
        float sh = be3[k] - mu * sc;
        float x = h[(size_t)r * 128 + k] * sc + sh;
        #pragma unroll
        for (int j = 0; j < 6; ++j) v[j] += x * fcW[k * 6 + j];
    }
    #pragma unroll
    for (int j = 0; j < 6; ++j)
        #pragma unroll
        for (int off = 32; off > 0; off >>= 1) v[j] += __shfl_down(v[j], off);
    if (lane == 0) {
        #pragma unroll
        for (int j = 0; j < 6; ++j) v[j] += fcb[j];
        float m = v[0];
        #pragma unroll
        for (int j = 1; j < 6; ++j) m = fmaxf(m, v[j]);
        float s = 0.f;
        #pragma unroll
        for (int j = 0; j < 6; ++j) s += expf(v[j] - m);
        float l = m + logf(s);
        #pragma unroll
        for (int j = 0; j < 6; ++j) out[r * 6 + j] = v[j] - l;
    }
}

// ---------------- launch ----------------

extern "C" void kernel_launch(void* const* d_in, const int* in_sizes, int n_in,
                              void* d_out, int out_size, void* d_ws, size_t ws_size,
                              hipStream_t stream) {
    (void)in_sizes; (void)n_in; (void)out_size; (void)ws_size;
    const float* x   = (const float*)d_in[0];
    const int*   ei  = (const int*)d_in[1];
    const float* ea  = (const float*)d_in[2];
    const float* W1  = (const float*)d_in[3];
    // b1/b2/b3 (d_in[4],[9],[15]) cancel under training-mode BN
    const float* g1  = (const float*)d_in[5];
    const float* be1 = (const float*)d_in[6];
    const float* W2a = (const float*)d_in[7];
    const float* W2b = (const float*)d_in[8];
    const float* g2  = (const float*)d_in[10];
    const float* be2 = (const float*)d_in[11];
    const float* W3a = (const float*)d_in[12];
    const float* W3b = (const float*)d_in[13];
    const float* W3c = (const float*)d_in[14];
    const float* g3  = (const float*)d_in[16];
    const float* be3 = (const float*)d_in[17];
    const float* fcW = (const float*)d_in[18];
    const float* fcb = (const float*)d_in[19];
    float* out = (float*)d_out;

    const int* src = ei;
    const int* dst = ei + N_EDGES;

    char* w = (char*)d_ws;
    size_t off = 0;
    auto alloc = [&](size_t bytes) -> void* {
        void* p = w + off;
        off += (bytes + 4095) & ~(size_t)4095;
        return p;
    };
    // zeroed region first
    float* deg    = (float*)alloc(N_NODES * 4);
    int*   cnt    = (int*)  alloc(N_NODES * 4);
    int*   fillc  = (int*)  alloc(N_NODES * 4);
    float* sums1  = (float*)alloc(1024 * 4);
    float* sums2  = (float*)alloc(1024 * 4);
    float* sums3  = (float*)alloc(1024 * 4);
    size_t zero_bytes = off;
    float* dis    = (float*)alloc(N_NODES * 4);
    int*   rowptr = (int*)  alloc((N_NODES + 1) * 4);
    int*   csr_s  = (int*)  alloc(N_EDGES * 4);
    float* csr_w  = (float*)alloc(N_EDGES * 4);
    us* B1T = (us*)alloc((size_t)512 * 1536 * 2);
    us* B2T = (us*)alloc((size_t)512 * 1024 * 2);
    us* B3T = (us*)alloc((size_t)384 * 512 * 2);
    // aliased big slots
    us* slotA = (us*)alloc((size_t)MPAD * 1536 * 2);          // A'1/A'2/A'3 (packed)
    float* slotG = (float*)alloc((size_t)N_NODES * 512 * 4);  // G1/G2/G3
    float* slotC = (float*)alloc((size_t)N_NODES * 256 * 4);  // out2 ; T|U
    float* bufF  = (float*)alloc((size_t)N_NODES * 128 * 4);

    us* A1 = slotA;
    us* A2 = slotA;
    us* A3 = slotA;
    float* G1 = slotG;
    float* G2 = slotG;
    float* G3 = slotG;
    float* out2 = slotC;
    float* bufT = slotC;
    float* bufU = slotC + (size_t)N_NODES * 128;

    hipMemsetAsync(d_ws, 0, zero_bytes, stream);

    // graph preprocessing -> dst-CSR with normalized weights
    deg_kernel<<<N_EDGES / 256, 256, 0, stream>>>(src, dst, ea, deg, cnt);
    dis_scan_kernel<<<40, 1024, 0, stream>>>(deg, cnt, dis, rowptr);
    fill_kernel<<<N_EDGES / 256, 256, 0, stream>>>(src, dst, ea, dis, rowptr, fillc,
                                                   csr_s, csr_w);

    // all fp32->bf16 hi/lo packed conversions in one dispatch
    cvt_all_kernel<<<2128, 256, 0, stream>>>(x, A1, W1, B1T, W2a, W2b, B2T,
                                             W3a, W3b, W3c, B3T);

    // ---- layer 1: G1 = x @ W1 (bf16x3) + fused BN stats; BN+ReLU+cvt -> A'2 ----
    mfma_gemm_kernel<<<632, 256, 0, stream>>>(A1, B1T, G1, N_NODES, 768, 512, 8, sums1);
    bn_relu_cvt_kernel<<<dim3(40, 32), 256, 0, stream>>>(G1, sums1, g1, be1, A2, 512);

    // ---- layer 2: G2 = h1 @ [W2a|W2b]; out2 = y0 + P y1 (+stats); cvt -> A'3 ----
    mfma_gemm_kernel<<<632, 256, 0, stream>>>(A2, B2T, G2, N_NODES, 512, 512, 8, nullptr);
    prop_l2_stats_kernel<<<625, 256, 0, stream>>>(G2, rowptr, csr_s, csr_w, out2, sums2);
    bn_relu_cvt_kernel<<<dim3(40, 16), 256, 0, stream>>>(out2, sums2, g2, be2, A3, 256);

    // ---- layer 3: G3 = h2 @ [W3a|W3b|W3c] = [f0|g1|g2] ----
    mfma_gemm_kernel<<<474, 256, 0, stream>>>(A3, B3T, G3, N_NODES, 256, 384, 6, nullptr);
    // t = P g2 ; u = P (g1 + 2 t) ; out3 = f0 - g2 + u
    prop_f128_kernel<<<N_NODES / 2, 256, 0, stream>>>(G3, 384, 256, nullptr, 0.f,
                                                      rowptr, csr_s, csr_w, bufT);
    prop_f128_kernel<<<N_NODES / 2, 256, 0, stream>>>(G3, 384, 128, bufT, 2.f,
                                                      rowptr, csr_s, csr_w, bufU);
    combine3_stats_kernel<<<125, 128, 0, stream>>>(G3, bufU, bufF, sums3);

    // ---- BN3 (inline coeffs) + FC + log_softmax fused ----
    final_kernel<<<2500, 256, 0, stream>>>(bufF, sums3, g3, be3, fcW, fcb, out);
}

// Round 6
// 385.311 us; speedup vs baseline: 1.2637x; 1.1153x over previous
//
#include <hip/hip_runtime.h>
#include <hip/hip_bf16.h>
#include <cstdint>

#define N_NODES 10000
#define N_EDGES 160000
#define MPAD    10112   // 79 * 128

typedef __attribute__((ext_vector_type(8))) short short8;
typedef __attribute__((ext_vector_type(4))) float floatx4;
typedef unsigned short us;

// ---------------- helpers ----------------

__device__ __forceinline__ us bf16_rn(float f) {
    union { float f; unsigned u; } c{f};
    unsigned r = c.u + 0x7FFF + ((c.u >> 16) & 1);   // round-to-nearest-even
    return (us)(r >> 16);
}
__device__ __forceinline__ float bf16_to_f(us h) {
    union { unsigned u; float f; } c{(unsigned)h << 16};
    return c.f;
}
__device__ __forceinline__ unsigned pack_hi2(float a, float b) {
    return (unsigned)bf16_rn(a) | ((unsigned)bf16_rn(b) << 16);
}
__device__ __forceinline__ unsigned pack_lo2(float a, float b) {
    float ra = a - bf16_to_f(bf16_rn(a));
    float rb = b - bf16_to_f(bf16_rn(b));
    return (unsigned)bf16_rn(ra) | ((unsigned)bf16_rn(rb) << 16);
}

__device__ __forceinline__ void gload_lds16(const void* g, void* l) {
    __builtin_amdgcn_global_load_lds(
        (const __attribute__((address_space(1))) unsigned int*)g,
        (__attribute__((address_space(3))) unsigned int*)l, 16, 0, 0);
}

// ================= tile-packed bf16 layouts (verified round 5) =================
// A_packed: per 128-row panel pa, per 32-k tile kt: 4096 elems as
//   elem((kq*128 + rr)*8 + e); width axis = [hi | lo] concat (2K).
// B_packed: per 64-col panel pb, per 32-k tile: 2048 elems, (kq*64 + c)*8 + e.

// ---------------- edge preprocessing ----------------

__global__ void deg_kernel(const int* __restrict__ src, const int* __restrict__ dst,
                           const float* __restrict__ ew,
                           float* __restrict__ deg, int* __restrict__ cnt) {
    int e = blockIdx.x * blockDim.x + threadIdx.x;
    if (e >= N_EDGES) return;
    atomicAdd(&deg[src[e]], ew[e]);
    atomicAdd(&cnt[dst[e]], 1);
}

// block 0: exclusive scan cnt -> rowptr ; blocks 1..39: dis = rsqrt(deg)
__global__ __launch_bounds__(1024) void dis_scan_kernel(const float* __restrict__ deg,
                                                        const int* __restrict__ cnt,
                                                        float* __restrict__ dis,
                                                        int* __restrict__ rowptr) {
    const int t = threadIdx.x;
    if (blockIdx.x != 0) {
        int n = (blockIdx.x - 1) * 1024 + t;
        if (n < N_NODES) {
            float d = deg[n];
            dis[n] = d > 0.f ? rsqrtf(d) : 0.f;
        }
        return;
    }
    __shared__ int wsum[16];
    const int lane = t & 63, wid = t >> 6;
    int carry = 0;
    for (int base = 0; base < N_NODES; base += 1024) {
        int i = base + t;
        int v = (i < N_NODES) ? cnt[i] : 0;
        int s = v;
        #pragma unroll
        for (int off = 1; off < 64; off <<= 1) {
            int u = __shfl_up(s, off);
            if (lane >= off) s += u;
        }
        if (lane == 63) wsum[wid] = s;
        __syncthreads();
        int woff = 0, tot = 0;
        for (int ww = 0; ww < 16; ++ww) {
            int xv = wsum[ww];
            if (ww < wid) woff += xv;
            tot += xv;
        }
        if (i < N_NODES) rowptr[i + 1] = carry + woff + s;
        carry += tot;
        __syncthreads();
    }
    if (t == 0) rowptr[0] = 0;
}

__global__ void fill_kernel(const int* __restrict__ src, const int* __restrict__ dst,
                            const float* __restrict__ ew, const float* __restrict__ dis,
                            const int* __restrict__ rowptr, int* __restrict__ fill,
                            int* __restrict__ csr_src, float* __restrict__ csr_w) {
    int e = blockIdx.x * blockDim.x + threadIdx.x;
    if (e >= N_EDGES) return;
    int s = src[e], d = dst[e];
    int pos = rowptr[d] + atomicAdd(&fill[d], 1);
    csr_src[pos] = s;
    csr_w[pos] = -dis[s] * ew[e] * dis[d];
}

// ---------------- packed conversions ----------------

__device__ __forceinline__ void cvt_x_body(int bx, int k16, const float* __restrict__ x,
                                           us* __restrict__ Ap) {
    int m = bx * 256 + threadIdx.x;
    if (m >= N_NODES) return;
    const float4* p = (const float4*)(x + (size_t)m * 768 + k16 * 16);
    float4 v0 = p[0], v1 = p[1], v2 = p[2], v3 = p[3];
    uint4 hi0, hi1, lo0, lo1;
    hi0.x = pack_hi2(v0.x, v0.y); hi0.y = pack_hi2(v0.z, v0.w);
    hi0.z = pack_hi2(v1.x, v1.y); hi0.w = pack_hi2(v1.z, v1.w);
    hi1.x = pack_hi2(v2.x, v2.y); hi1.y = pack_hi2(v2.z, v2.w);
    hi1.z = pack_hi2(v3.x, v3.y); hi1.w = pack_hi2(v3.z, v3.w);
    lo0.x = pack_lo2(v0.x, v0.y); lo0.y = pack_lo2(v0.z, v0.w);
    lo0.z = pack_lo2(v1.x, v1.y); lo0.w = pack_lo2(v1.z, v1.w);
    lo1.x = pack_lo2(v2.x, v2.y); lo1.y = pack_lo2(v2.z, v2.w);
    lo1.z = pack_lo2(v3.x, v3.y); lo1.w = pack_lo2(v3.z, v3.w);
    int pa = m >> 7, rr = m & 127;
    int kt = k16 >> 1, kqb = (k16 & 1) * 2;
    size_t th = ((size_t)pa * 48 + kt) * 4096;
    size_t tl = ((size_t)pa * 48 + 24 + kt) * 4096;
    *(uint4*)&Ap[th + ((kqb + 0) * 128 + rr) * 8] = hi0;
    *(uint4*)&Ap[th + ((kqb + 1) * 128 + rr) * 8] = hi1;
    *(uint4*)&Ap[tl + ((kqb + 0) * 128 + rr) * 8] = lo0;
    *(uint4*)&Ap[tl + ((kqb + 1) * 128 + rr) * 8] = lo1;
}

__device__ __forceinline__ void cvt_w_body(int bx, int k16, const float* __restrict__ W,
                                           us* __restrict__ Bp, int K, int N) {
    int n = bx * 256 + threadIdx.x;
    if (n >= N) return;
    float v[16];
    #pragma unroll
    for (int j = 0; j < 16; ++j) v[j] = W[(size_t)(k16 * 16 + j) * N + n];
    uint4 hi0, hi1, lo0, lo1;
    hi0.x = pack_hi2(v[0], v[1]);  hi0.y = pack_hi2(v[2], v[3]);
    hi0.z = pack_hi2(v[4], v[5]);  hi0.w = pack_hi2(v[6], v[7]);
    hi1.x = pack_hi2(v[8], v[9]);  hi1.y = pack_hi2(v[10], v[11]);
    hi1.z = pack_hi2(v[12], v[13]); hi1.w = pack_hi2(v[14], v[15]);
    lo0.x = pack_lo2(v[0], v[1]);  lo0.y = pack_lo2(v[2], v[3]);
    lo0.z = pack_lo2(v[4], v[5]);  lo0.w = pack_lo2(v[6], v[7]);
    lo1.x = pack_lo2(v[8], v[9]);  lo1.y = pack_lo2(v[10], v[11]);
    lo1.z = pack_lo2(v[12], v[13]); lo1.w = pack_lo2(v[14], v[15]);
    int pb = n >> 6, c = n & 63;
    int NKTB = K >> 4;
    int kt = k16 >> 1, kqb = (k16 & 1) * 2;
    size_t th = ((size_t)pb * NKTB + kt) * 2048;
    size_t tl = ((size_t)pb * NKTB + (K >> 5) + kt) * 2048;
    *(uint4*)&Bp[th + ((kqb + 0) * 64 + c) * 8] = hi0;
    *(uint4*)&Bp[th + ((kqb + 1) * 64 + c) * 8] = hi1;
    *(uint4*)&Bp[tl + ((kqb + 0) * 64 + c) * 8] = lo0;
    *(uint4*)&Bp[tl + ((kqb + 1) * 64 + c) * 8] = lo1;
}

__global__ __launch_bounds__(256) void cvt_all_kernel(const float* __restrict__ x,
                                                      us* __restrict__ A1,
                                                      const float* __restrict__ W1,
                                                      us* __restrict__ B1T,
                                                      const float* __restrict__ W2a,
                                                      const float* __restrict__ W2b,
                                                      us* __restrict__ B2T,
                                                      const float* __restrict__ W3a,
                                                      const float* __restrict__ W3b,
                                                      const float* __restrict__ W3c,
                                                      us* __restrict__ B3T) {
    int b = blockIdx.x;
    if (b < 1920) { cvt_x_body(b % 40, b / 40, x, A1); return; }
    b -= 1920;
    if (b < 96)  { cvt_w_body(b & 1, b >> 1, W1, B1T, 768, 512); return; }
    b -= 96;
    if (b < 32)  { cvt_w_body(0, b, W2a, B2T, 512, 256); return; }
    b -= 32;
    if (b < 32)  { cvt_w_body(0, b, W2b, B2T + (size_t)4 * 32 * 2048, 512, 256); return; }
    b -= 32;
    if (b < 16)  { cvt_w_body(0, b, W3a, B3T, 256, 128); return; }
    b -= 16;
    if (b < 16)  { cvt_w_body(0, b, W3b, B3T + (size_t)2 * 16 * 2048, 256, 128); return; }
    b -= 16;
    cvt_w_body(0, b, W3c, B3T + (size_t)4 * 16 * 2048, 256, 128);
}

// fused BN(inline coeffs)+ReLU+cvt -> packed A. grid (40, F/16)
__global__ __launch_bounds__(256) void bn_relu_cvt_kernel(const float* __restrict__ G,
                                                          const float* __restrict__ sums,
                                                          const float* __restrict__ g,
                                                          const float* __restrict__ be,
                                                          us* __restrict__ Ap, int F) {
    const int k16 = blockIdx.y;
    int m = blockIdx.x * 256 + threadIdx.x;
    if (m >= N_NODES) return;
    const float invM = 1.0f / (float)N_NODES;
    float sc[16], sh[16];
    #pragma unroll
    for (int j = 0; j < 16; ++j) {
        int c = k16 * 16 + j;
        float mu = sums[c] * invM;
        float s = g[c] * rsqrtf(sums[F + c] * invM - mu * mu + 1e-5f);
        sc[j] = s;
        sh[j] = be[c] - mu * s;
    }
    const float4* p = (const float4*)(G + (size_t)m * F + k16 * 16);
    float v[16];
    #pragma unroll
    for (int q = 0; q < 4; ++q) {
        float4 t4 = p[q];
        v[q * 4 + 0] = t4.x; v[q * 4 + 1] = t4.y;
        v[q * 4 + 2] = t4.z; v[q * 4 + 3] = t4.w;
    }
    #pragma unroll
    for (int j = 0; j < 16; ++j) v[j] = fmaxf(v[j] * sc[j] + sh[j], 0.f);
    uint4 hi0, hi1, lo0, lo1;
    hi0.x = pack_hi2(v[0], v[1]);  hi0.y = pack_hi2(v[2], v[3]);
    hi0.z = pack_hi2(v[4], v[5]);  hi0.w = pack_hi2(v[6], v[7]);
    hi1.x = pack_hi2(v[8], v[9]);  hi1.y = pack_hi2(v[10], v[11]);
    hi1.z = pack_hi2(v[12], v[13]); hi1.w = pack_hi2(v[14], v[15]);
    lo0.x = pack_lo2(v[0], v[1]);  lo0.y = pack_lo2(v[2], v[3]);
    lo0.z = pack_lo2(v[4], v[5]);  lo0.w = pack_lo2(v[6], v[7]);
    lo1.x = pack_lo2(v[8], v[9]);  lo1.y = pack_lo2(v[10], v[11]);
    lo1.z = pack_lo2(v[12], v[13]); lo1.w = pack_lo2(v[14], v[15]);
    int pa = m >> 7, rr = m & 127;
    int NKT = F >> 4;
    int kt = k16 >> 1, kqb = (k16 & 1) * 2;
    size_t th = ((size_t)pa * NKT + kt) * 4096;
    size_t tl = ((size_t)pa * NKT + (F >> 5) + kt) * 4096;
    *(uint4*)&Ap[th + ((kqb + 0) * 128 + rr) * 8] = hi0;
    *(uint4*)&Ap[th + ((kqb + 1) * 128 + rr) * 8] = hi1;
    *(uint4*)&Ap[tl + ((kqb + 0) * 128 + rr) * 8] = lo0;
    *(uint4*)&Ap[tl + ((kqb + 1) * 128 + rr) * 8] = lo1;
}

// ---------------- bf16x3 MFMA GEMM: 128x64 tile, packed tiles (round-5) ----------------

__global__ __launch_bounds__(256, 4) void mfma_gemm_kernel(
        const us* __restrict__ Ap,
        const us* __restrict__ BpT,
        float* __restrict__ C,
        int M, int Ksub, int Nc, int ncb,
        float* __restrict__ sums) {
    __shared__ us As[4096];
    __shared__ us Bs[2048];
    const int t = threadIdx.x;
    const int w = t >> 6, l = t & 63;

    int nwg = gridDim.x, bid = blockIdx.x;
    int q = nwg >> 3, r = nwg & 7;
    int xcd = bid & 7, idx = bid >> 3;
    int wgid = (xcd < r ? xcd * (q + 1) : r * (q + 1) + (xcd - r) * q) + idx;
    const int row0 = (wgid / ncb) * 128;
    const int col0 = (wgid % ncb) * 64;

    const int NKTA = Ksub >> 4;
    const int Ktot = 3 * Ksub;
    const int wr = w >> 1, wc = w & 1;
    const int lr = l & 15, kq = l >> 4;

    const size_t Abase = (size_t)(row0 >> 7) * NKTA * 4096;
    const size_t Bbase = (size_t)(col0 >> 6) * NKTA * 2048;

    floatx4 acc[4][2] = {};

    for (int k0 = 0; k0 < Ktot; k0 += 32) {
        int kA = (k0 < 2 * Ksub) ? k0 : k0 - 2 * Ksub;
        int kB = (k0 < Ksub)     ? k0 : k0 - Ksub;
        const us* At = Ap + Abase + (size_t)(kA >> 5) * 4096;
        const us* Bt = BpT + Bbase + (size_t)(kB >> 5) * 2048;
        gload_lds16(At + (w * 64 + l) * 8,       (char*)As + w * 1024);
        gload_lds16(At + ((w + 4) * 64 + l) * 8, (char*)As + (w + 4) * 1024);
        gload_lds16(Bt + (w * 64 + l) * 8,       (char*)Bs + w * 1024);
        __syncthreads();
        short8 af[4], bfr[2];
        #pragma unroll
        for (int m = 0; m < 4; ++m)
            af[m] = *(const short8*)&As[(kq * 128 + wr * 64 + m * 16 + lr) * 8];
        #pragma unroll
        for (int n = 0; n < 2; ++n)
            bfr[n] = *(const short8*)&Bs[(kq * 64 + wc * 32 + n * 16 + lr) * 8];
        #pragma unroll
        for (int m = 0; m < 4; ++m)
            #pragma unroll
            for (int n = 0; n < 2; ++n)
                acc[m][n] = __builtin_amdgcn_mfma_f32_16x16x32_bf16(
                    af[m], bfr[n], acc[m][n], 0, 0, 0);
        __syncthreads();
    }

    #pragma unroll
    for (int m = 0; m < 4; ++m) {
        int rb = row0 + wr * 64 + m * 16 + kq * 4;
        #pragma unroll
        for (int j = 0; j < 4; ++j) {
            int rr = rb + j;
            if (rr < M) {
                #pragma unroll
                for (int n = 0; n < 2; ++n)
                    C[(size_t)rr * Nc + col0 + wc * 32 + n * 16 + lr] = acc[m][n][j];
            }
        }
    }

    if (sums) {
        float s[2] = {0.f, 0.f}, qv[2] = {0.f, 0.f};
        #pragma unroll
        for (int m = 0; m < 4; ++m)
            #pragma unroll
            for (int n = 0; n < 2; ++n)
                #pragma unroll
                for (int j = 0; j < 4; ++j) {
                    float v = acc[m][n][j];
                    s[n] += v; qv[n] += v * v;
                }
        float* red = (float*)As;
        int g8 = wr * 4 + kq;
        #pragma unroll
        for (int n = 0; n < 2; ++n) {
            int c = wc * 32 + n * 16 + lr;
            red[g8 * 128 + c * 2 + 0] = s[n];
            red[g8 * 128 + c * 2 + 1] = qv[n];
        }
        __syncthreads();
        if (t < 128) {
            float tot = 0.f;
            #pragma unroll
            for (int g = 0; g < 8; ++g) tot += red[g * 128 + t];
            int c = t >> 1, e = t & 1;
            atomicAdd(&sums[e * 512 + col0 + c], tot);
        }
    }
}

// ---------------- graph propagation (v2: float4 gathers, max TLP) ----------------

// out2[n][f] = G2[n][f] + sum_e w * G2[src][256+f]. 4 nodes/block (64 lanes each).
__global__ __launch_bounds__(256) void prop_l2_kernel(const float* __restrict__ G2,
                                                      const int* __restrict__ rowptr,
                                                      const int* __restrict__ csr_s,
                                                      const float* __restrict__ csr_w,
                                                      float* __restrict__ out2) {
    const int g = threadIdx.x >> 6, lane = threadIdx.x & 63;
    const int n = blockIdx.x * 4 + g;
    const int f4 = lane * 4;
    float4 acc = {0.f, 0.f, 0.f, 0.f};
    int e = rowptr[n];
    const int e1 = rowptr[n + 1];
    for (; e + 1 < e1; e += 2) {
        int s0 = csr_s[e], s1 = csr_s[e + 1];
        float w0 = csr_w[e], w1 = csr_w[e + 1];
        float4 a = *(const float4*)&G2[(size_t)s0 * 512 + 256 + f4];
        float4 b = *(const float4*)&G2[(size_t)s1 * 512 + 256 + f4];
        acc.x += w0 * a.x + w1 * b.x; acc.y += w0 * a.y + w1 * b.y;
        acc.z += w0 * a.z + w1 * b.z; acc.w += w0 * a.w + w1 * b.w;
    }
    if (e < e1) {
        float w0 = csr_w[e];
        float4 a = *(const float4*)&G2[(size_t)csr_s[e] * 512 + 256 + f4];
        acc.x += w0 * a.x; acc.y += w0 * a.y; acc.z += w0 * a.z; acc.w += w0 * a.w;
    }
    float4 base = *(const float4*)&G2[(size_t)n * 512 + f4];
    acc.x += base.x; acc.y += base.y; acc.z += base.z; acc.w += base.w;
    *(float4*)&out2[(size_t)n * 256 + f4] = acc;
}

// streaming BN stats over out2 (F=256): 500 blocks x 20 rows
__global__ __launch_bounds__(256) void bn_stats256_kernel(const float* __restrict__ h,
                                                          float* __restrict__ sums) {
    const int t = threadIdx.x;
    int r0 = blockIdx.x * 20, r1 = min(r0 + 20, N_NODES);
    float s = 0.f, q = 0.f;
    for (int r = r0; r < r1; ++r) {
        float v = h[(size_t)r * 256 + t];
        s += v; q += v * v;
    }
    atomicAdd(&sums[t], s);
    atomicAdd(&sums[256 + t], q);
}

// T[n][f] = sum_e w * G3[src][256+f]. 8 nodes/block (32 lanes x float4).
__global__ __launch_bounds__(256) void prop3a_kernel(const float* __restrict__ G3,
                                                     const int* __restrict__ rowptr,
                                                     const int* __restrict__ csr_s,
                                                     const float* __restrict__ csr_w,
                                                     float* __restrict__ T) {
    const int g = threadIdx.x >> 5, lane = threadIdx.x & 31;
    const int n = blockIdx.x * 8 + g;
    const int f4 = lane * 4;
    float4 acc = {0.f, 0.f, 0.f, 0.f};
    int e = rowptr[n];
    const int e1 = rowptr[n + 1];
    for (; e + 1 < e1; e += 2) {
        int s0 = csr_s[e], s1 = csr_s[e + 1];
        float w0 = csr_w[e], w1 = csr_w[e + 1];
        float4 a = *(const float4*)&G3[(size_t)s0 * 384 + 256 + f4];
        float4 b = *(const float4*)&G3[(size_t)s1 * 384 + 256 + f4];
        acc.x += w0 * a.x + w1 * b.x; acc.y += w0 * a.y + w1 * b.y;
        acc.z += w0 * a.z + w1 * b.z; acc.w += w0 * a.w + w1 * b.w;
    }
    if (e < e1) {
        float w0 = csr_w[e];
        float4 a = *(const float4*)&G3[(size_t)csr_s[e] * 384 + 256 + f4];
        acc.x += w0 * a.x; acc.y += w0 * a.y; acc.z += w0 * a.z; acc.w += w0 * a.w;
    }
    *(float4*)&T[(size_t)n * 128 + f4] = acc;
}

// U = P(g1 + 2T) ; out3 = f0 - g2 + U ; fused BN stats. 8 nodes/block.
__global__ __launch_bounds__(256) void prop3b_combine_kernel(const float* __restrict__ G3,
                                                             const float* __restrict__ T,
                                                             const int* __restrict__ rowptr,
                                                             const int* __restrict__ csr_s,
                                                             const float* __restrict__ csr_w,
                                                             float* __restrict__ Fbuf,
                                                             float* __restrict__ sums) {
    __shared__ float red_s[8][128];
    __shared__ float red_q[8][128];
    const int g = threadIdx.x >> 5, lane = threadIdx.x & 31;
    const int n = blockIdx.x * 8 + g;
    const int f4 = lane * 4;
    float4 acc = {0.f, 0.f, 0.f, 0.f};
    int e = rowptr[n];
    const int e1 = rowptr[n + 1];
    for (; e < e1; ++e) {
        int s = csr_s[e];
        float w0 = csr_w[e];
        float4 a = *(const float4*)&G3[(size_t)s * 384 + 128 + f4];
        float4 b = *(const float4*)&T[(size_t)s * 128 + f4];
        acc.x += w0 * (a.x + 2.f * b.x); acc.y += w0 * (a.y + 2.f * b.y);
        acc.z += w0 * (a.z + 2.f * b.z); acc.w += w0 * (a.w + 2.f * b.w);
    }
    float4 p = *(const float4*)&G3[(size_t)n * 384 + f4];
    float4 r = *(const float4*)&G3[(size_t)n * 384 + 256 + f4];
    float4 v;
    v.x = p.x - r.x + acc.x; v.y = p.y - r.y + acc.y;
    v.z = p.z - r.z + acc.z; v.w = p.w - r.w + acc.w;
    *(float4*)&Fbuf[(size_t)n * 128 + f4] = v;
    red_s[g][f4 + 0] = v.x; red_s[g][f4 + 1] = v.y;
    red_s[g][f4 + 2] = v.z; red_s[g][f4 + 3] = v.w;
    red_q[g][f4 + 0] = v.x * v.x; red_q[g][f4 + 1] = v.y * v.y;
    red_q[g][f4 + 2] = v.z * v.z; red_q[g][f4 + 3] = v.w * v.w;
    __syncthreads();
    const int t = threadIdx.x;
    if (t < 128) {
        float s = 0.f, q = 0.f;
        #pragma unroll
        for (int gg = 0; gg < 8; ++gg) { s += red_s[gg][t]; q += red_q[gg][t]; }
        atomicAdd(&sums[t], s);
        atomicAdd(&sums[128 + t], q);
    }
}

// ---------------- fused BN3 (inline coeffs) + FC(128->6) + log_softmax ----------------

__global__ __launch_bounds__(256) void final_kernel(const float* __restrict__ h,
                                                    const float* __restrict__ sums,
                                                    const float* __restrict__ g3,
                                                    const float* __restrict__ be3,
                                                    const float* __restrict__ fcW,
                                                    const float* __restrict__ fcb,
                                                    float* __restrict__ out) {
    const int t = threadIdx.x, lane = t & 63, wid = t >> 6;
    const int r = blockIdx.x * 4 + wid;
    if (r >= N_NODES) return;
    const float invM = 1.0f / (float)N_NODES;
    float v[6] = {0.f, 0.f, 0.f, 0.f, 0.f, 0.f};
    #pragma unroll
    for (int kk = 0; kk < 2; ++kk) {
        int k = lane + kk * 64;
        float mu = sums[k] * invM;
        float sc = g3[k] * rsqrtf(sums[128 + k] * invM - mu * mu + 1e-5f);
        float sh = be3[k] - mu * sc;
        float x = h[(size_t)r * 128 + k] * sc + sh;
        #pragma unroll
        for (int j = 0; j < 6; ++j) v[j] += x * fcW[k * 6 + j];
    }
    #pragma unroll
    for (int j = 0; j < 6; ++j)
        #pragma unroll
        for (int off = 32; off > 0; off >>= 1) v[j] += __shfl_down(v[j], off);
    if (lane == 0) {
        #pragma unroll
        for (int j = 0; j < 6; ++j) v[j] += fcb[j];
        float m = v[0];
        #pragma unroll
        for (int j = 1; j < 6; ++j) m = fmaxf(m, v[j]);
        float s = 0.f;
        #pragma unroll
        for (int j = 0; j < 6; ++j) s += expf(v[j] - m);
        float l = m + logf(s);
        #pragma unroll
        for (int j = 0; j < 6; ++j) out[r * 6 + j] = v[j] - l;
    }
}

// ---------------- launch ----------------

extern "C" void kernel_launch(void* const* d_in, const int* in_sizes, int n_in,
                              void* d_out, int out_size, void* d_ws, size_t ws_size,
                              hipStream_t stream) {
    (void)in_sizes; (void)n_in; (void)out_size; (void)ws_size;
    const float* x   = (const float*)d_in[0];
    const int*   ei  = (const int*)d_in[1];
    const float* ea  = (const float*)d_in[2];
    const float* W1  = (const float*)d_in[3];
    // b1/b2/b3 (d_in[4],[9],[15]) cancel under training-mode BN
    const float* g1  = (const float*)d_in[5];
    const float* be1 = (const float*)d_in[6];
    const float* W2a = (const float*)d_in[7];
    const float* W2b = (const float*)d_in[8];
    const float* g2  = (const float*)d_in[10];
    const float* be2 = (const float*)d_in[11];
    const float* W3a = (const float*)d_in[12];
    const float* W3b = (const float*)d_in[13];
    const float* W3c = (const float*)d_in[14];
    const float* g3  = (const float*)d_in[16];
    const float* be3 = (const float*)d_in[17];
    const float* fcW = (const float*)d_in[18];
    const float* fcb = (const float*)d_in[19];
    float* out = (float*)d_out;

    const int* src = ei;
    const int* dst = ei + N_EDGES;

    char* w = (char*)d_ws;
    size_t off = 0;
    auto alloc = [&](size_t bytes) -> void* {
        void* p = w + off;
        off += (bytes + 4095) & ~(size_t)4095;
        return p;
    };
    // zeroed region first
    float* deg    = (float*)alloc(N_NODES * 4);
    int*   cnt    = (int*)  alloc(N_NODES * 4);
    int*   fillc  = (int*)  alloc(N_NODES * 4);
    float* sums1  = (float*)alloc(1024 * 4);
    float* sums2  = (float*)alloc(1024 * 4);
    float* sums3  = (float*)alloc(1024 * 4);
    size_t zero_bytes = off;
    float* dis    = (float*)alloc(N_NODES * 4);
    int*   rowptr = (int*)  alloc((N_NODES + 1) * 4);
    int*   csr_s  = (int*)  alloc(N_EDGES * 4);
    float* csr_w  = (float*)alloc(N_EDGES * 4);
    us* B1T = (us*)alloc((size_t)512 * 1536 * 2);
    us* B2T = (us*)alloc((size_t)512 * 1024 * 2);
    us* B3T = (us*)alloc((size_t)384 * 512 * 2);
    // aliased big slots
    us* slotA = (us*)alloc((size_t)MPAD * 1536 * 2);          // A'1/A'2/A'3 (packed)
    float* slotG = (float*)alloc((size_t)N_NODES * 512 * 4);  // G1/G2/G3
    float* slotC = (float*)alloc((size_t)N_NODES * 256 * 4);  // out2 ; then T
    float* bufF  = (float*)alloc((size_t)N_NODES * 128 * 4);

    us* A1 = slotA;
    us* A2 = slotA;
    us* A3 = slotA;
    float* G1 = slotG;
    float* G2 = slotG;
    float* G3 = slotG;
    float* out2 = slotC;
    float* bufT = slotC;     // overwrites out2 after it is consumed

    hipMemsetAsync(d_ws, 0, zero_bytes, stream);

    // graph preprocessing -> dst-CSR with normalized weights
    deg_kernel<<<N_EDGES / 256, 256, 0, stream>>>(src, dst, ea, deg, cnt);
    dis_scan_kernel<<<40, 1024, 0, stream>>>(deg, cnt, dis, rowptr);
    fill_kernel<<<N_EDGES / 256, 256, 0, stream>>>(src, dst, ea, dis, rowptr, fillc,
                                                   csr_s, csr_w);

    // all fp32->bf16 hi/lo packed conversions in one dispatch
    cvt_all_kernel<<<2128, 256, 0, stream>>>(x, A1, W1, B1T, W2a, W2b, B2T,
                                             W3a, W3b, W3c, B3T);

    // ---- layer 1: G1 = x @ W1 (bf16x3) + fused BN stats; BN+ReLU+cvt -> A'2 ----
    mfma_gemm_kernel<<<632, 256, 0, stream>>>(A1, B1T, G1, N_NODES, 768, 512, 8, sums1);
    bn_relu_cvt_kernel<<<dim3(40, 32), 256, 0, stream>>>(G1, sums1, g1, be1, A2, 512);

    // ---- layer 2: G2 = h1 @ [W2a|W2b]; out2 = y0 + P y1; stats; cvt -> A'3 ----
    mfma_gemm_kernel<<<632, 256, 0, stream>>>(A2, B2T, G2, N_NODES, 512, 512, 8, nullptr);
    prop_l2_kernel<<<2500, 256, 0, stream>>>(G2, rowptr, csr_s, csr_w, out2);
    bn_stats256_kernel<<<500, 256, 0, stream>>>(out2, sums2);
    bn_relu_cvt_kernel<<<dim3(40, 16), 256, 0, stream>>>(out2, sums2, g2, be2, A3, 256);

    // ---- layer 3: G3 = h2 @ [W3a|W3b|W3c] = [f0|g1|g2] ----
    mfma_gemm_kernel<<<474, 256, 0, stream>>>(A3, B3T, G3, N_NODES, 256, 384, 6, nullptr);
    // T = P g2 ; U = P(g1 + 2T) ; out3 = f0 - g2 + U  (+ fused BN stats)
    prop3a_kernel<<<1250, 256, 0, stream>>>(G3, rowptr, csr_s, csr_w, bufT);
    prop3b_combine_kernel<<<1250, 256, 0, stream>>>(G3, bufT, rowptr, csr_s, csr_w,
                                                    bufF, sums3);

    // ---- BN3 (inline coeffs) + FC + log_softmax fused ----
    final_kernel<<<2500, 256, 0, stream>>>(bufF, sums3, g3, be3, fcW, fcb, out);
}

// Round 9
// 357.169 us; speedup vs baseline: 1.3633x; 1.0788x over previous
//
#include <hip/hip_runtime.h>
#include <hip/hip_bf16.h>
#include <cstdint>

#define N_NODES 10000
#define N_EDGES 160000
#define MPAD    10112   // 79 * 128

typedef __attribute__((ext_vector_type(8))) short short8;
typedef __attribute__((ext_vector_type(4))) float floatx4;
typedef unsigned short us;

// ---------------- helpers ----------------

__device__ __forceinline__ us bf16_rn(float f) {
    union { float f; unsigned u; } c{f};
    unsigned r = c.u + 0x7FFF + ((c.u >> 16) & 1);   // round-to-nearest-even
    return (us)(r >> 16);
}
__device__ __forceinline__ float bf16_to_f(us h) {
    union { unsigned u; float f; } c{(unsigned)h << 16};
    return c.f;
}
__device__ __forceinline__ unsigned pack_hi2(float a, float b) {
    return (unsigned)bf16_rn(a) | ((unsigned)bf16_rn(b) << 16);
}
__device__ __forceinline__ unsigned pack_lo2(float a, float b) {
    float ra = a - bf16_to_f(bf16_rn(a));
    float rb = b - bf16_to_f(bf16_rn(b));
    return (unsigned)bf16_rn(ra) | ((unsigned)bf16_rn(rb) << 16);
}

__device__ __forceinline__ void gload_lds16(const void* g, void* l) {
    __builtin_amdgcn_global_load_lds(
        (const __attribute__((address_space(1))) unsigned int*)g,
        (__attribute__((address_space(3))) unsigned int*)l, 16, 0, 0);
}

// ================= tile-packed bf16 layouts (verified round 5) =================
// A_packed: per 128-row panel pa, per 32-k tile kt: 4096 elems as
//   elem((kq*128 + rr)*8 + e); width axis = [hi | lo] concat (2K).
// B_packed: per 64-col panel pb, per 32-k tile: 2048 elems, (kq*64 + c)*8 + e.

// ---------------- edge preprocessing ----------------

__global__ void deg_kernel(const int* __restrict__ src, const int* __restrict__ dst,
                           const float* __restrict__ ew,
                           float* __restrict__ deg, int* __restrict__ cnt) {
    int e = blockIdx.x * blockDim.x + threadIdx.x;
    if (e >= N_EDGES) return;
    atomicAdd(&deg[src[e]], ew[e]);
    atomicAdd(&cnt[dst[e]], 1);
}

// block 0: exclusive scan cnt -> rowptr ; blocks 1..39: dis = rsqrt(deg)
__global__ __launch_bounds__(1024) void dis_scan_kernel(const float* __restrict__ deg,
                                                        const int* __restrict__ cnt,
                                                        float* __restrict__ dis,
                                                        int* __restrict__ rowptr) {
    const int t = threadIdx.x;
    if (blockIdx.x != 0) {
        int n = (blockIdx.x - 1) * 1024 + t;
        if (n < N_NODES) {
            float d = deg[n];
            dis[n] = d > 0.f ? rsqrtf(d) : 0.f;
        }
        return;
    }
    __shared__ int wsum[16];
    const int lane = t & 63, wid = t >> 6;
    int carry = 0;
    for (int base = 0; base < N_NODES; base += 1024) {
        int i = base + t;
        int v = (i < N_NODES) ? cnt[i] : 0;
        int s = v;
        #pragma unroll
        for (int off = 1; off < 64; off <<= 1) {
            int u = __shfl_up(s, off);
            if (lane >= off) s += u;
        }
        if (lane == 63) wsum[wid] = s;
        __syncthreads();
        int woff = 0, tot = 0;
        for (int ww = 0; ww < 16; ++ww) {
            int xv = wsum[ww];
            if (ww < wid) woff += xv;
            tot += xv;
        }
        if (i < N_NODES) rowptr[i + 1] = carry + woff + s;
        carry += tot;
        __syncthreads();
    }
    if (t == 0) rowptr[0] = 0;
}

__global__ void fill_kernel(const int* __restrict__ src, const int* __restrict__ dst,
                            const float* __restrict__ ew, const float* __restrict__ dis,
                            const int* __restrict__ rowptr, int* __restrict__ fill,
                            int* __restrict__ csr_src, float* __restrict__ csr_w) {
    int e = blockIdx.x * blockDim.x + threadIdx.x;
    if (e >= N_EDGES) return;
    int s = src[e], d = dst[e];
    int pos = rowptr[d] + atomicAdd(&fill[d], 1);
    csr_src[pos] = s;
    csr_w[pos] = -dis[s] * ew[e] * dis[d];
}

// ---------------- packed conversions ----------------

__device__ __forceinline__ void cvt_x_body(int bx, int k16, const float* __restrict__ x,
                                           us* __restrict__ Ap) {
    int m = bx * 256 + threadIdx.x;
    if (m >= N_NODES) return;
    const float4* p = (const float4*)(x + (size_t)m * 768 + k16 * 16);
    float4 v0 = p[0], v1 = p[1], v2 = p[2], v3 = p[3];
    uint4 hi0, hi1, lo0, lo1;
    hi0.x = pack_hi2(v0.x, v0.y); hi0.y = pack_hi2(v0.z, v0.w);
    hi0.z = pack_hi2(v1.x, v1.y); hi0.w = pack_hi2(v1.z, v1.w);
    hi1.x = pack_hi2(v2.x, v2.y); hi1.y = pack_hi2(v2.z, v2.w);
    hi1.z = pack_hi2(v3.x, v3.y); hi1.w = pack_hi2(v3.z, v3.w);
    lo0.x = pack_lo2(v0.x, v0.y); lo0.y = pack_lo2(v0.z, v0.w);
    lo0.z = pack_lo2(v1.x, v1.y); lo0.w = pack_lo2(v1.z, v1.w);
    lo1.x = pack_lo2(v2.x, v2.y); lo1.y = pack_lo2(v2.z, v2.w);
    lo1.z = pack_lo2(v3.x, v3.y); lo1.w = pack_lo2(v3.z, v3.w);
    int pa = m >> 7, rr = m & 127;
    int kt = k16 >> 1, kqb = (k16 & 1) * 2;
    size_t th = ((size_t)pa * 48 + kt) * 4096;
    size_t tl = ((size_t)pa * 48 + 24 + kt) * 4096;
    *(uint4*)&Ap[th + ((kqb + 0) * 128 + rr) * 8] = hi0;
    *(uint4*)&Ap[th + ((kqb + 1) * 128 + rr) * 8] = hi1;
    *(uint4*)&Ap[tl + ((kqb + 0) * 128 + rr) * 8] = lo0;
    *(uint4*)&Ap[tl + ((kqb + 1) * 128 + rr) * 8] = lo1;
}

__device__ __forceinline__ void cvt_w_body(int bx, int k16, const float* __restrict__ W,
                                           us* __restrict__ Bp, int K, int N) {
    int n = bx * 256 + threadIdx.x;
    if (n >= N) return;
    float v[16];
    #pragma unroll
    for (int j = 0; j < 16; ++j) v[j] = W[(size_t)(k16 * 16 + j) * N + n];
    uint4 hi0, hi1, lo0, lo1;
    hi0.x = pack_hi2(v[0], v[1]);  hi0.y = pack_hi2(v[2], v[3]);
    hi0.z = pack_hi2(v[4], v[5]);  hi0.w = pack_hi2(v[6], v[7]);
    hi1.x = pack_hi2(v[8], v[9]);  hi1.y = pack_hi2(v[10], v[11]);
    hi1.z = pack_hi2(v[12], v[13]); hi1.w = pack_hi2(v[14], v[15]);
    lo0.x = pack_lo2(v[0], v[1]);  lo0.y = pack_lo2(v[2], v[3]);
    lo0.z = pack_lo2(v[4], v[5]);  lo0.w = pack_lo2(v[6], v[7]);
    lo1.x = pack_lo2(v[8], v[9]);  lo1.y = pack_lo2(v[10], v[11]);
    lo1.z = pack_lo2(v[12], v[13]); lo1.w = pack_lo2(v[14], v[15]);
    int pb = n >> 6, c = n & 63;
    int NKTB = K >> 4;
    int kt = k16 >> 1, kqb = (k16 & 1) * 2;
    size_t th = ((size_t)pb * NKTB + kt) * 2048;
    size_t tl = ((size_t)pb * NKTB + (K >> 5) + kt) * 2048;
    *(uint4*)&Bp[th + ((kqb + 0) * 64 + c) * 8] = hi0;
    *(uint4*)&Bp[th + ((kqb + 1) * 64 + c) * 8] = hi1;
    *(uint4*)&Bp[tl + ((kqb + 0) * 64 + c) * 8] = lo0;
    *(uint4*)&Bp[tl + ((kqb + 1) * 64 + c) * 8] = lo1;
}

__global__ __launch_bounds__(256) void cvt_all_kernel(const float* __restrict__ x,
                                                      us* __restrict__ A1,
                                                      const float* __restrict__ W1,
                                                      us* __restrict__ B1T,
                                                      const float* __restrict__ W2a,
                                                      const float* __restrict__ W2b,
                                                      us* __restrict__ B2T,
                                                      const float* __restrict__ W3a,
                                                      const float* __restrict__ W3b,
                                                      const float* __restrict__ W3c,
                                                      us* __restrict__ B3T) {
    int b = blockIdx.x;
    if (b < 1920) { cvt_x_body(b % 40, b / 40, x, A1); return; }
    b -= 1920;
    if (b < 96)  { cvt_w_body(b & 1, b >> 1, W1, B1T, 768, 512); return; }
    b -= 96;
    if (b < 32)  { cvt_w_body(0, b, W2a, B2T, 512, 256); return; }
    b -= 32;
    if (b < 32)  { cvt_w_body(0, b, W2b, B2T + (size_t)4 * 32 * 2048, 512, 256); return; }
    b -= 32;
    if (b < 16)  { cvt_w_body(0, b, W3a, B3T, 256, 128); return; }
    b -= 16;
    if (b < 16)  { cvt_w_body(0, b, W3b, B3T + (size_t)2 * 16 * 2048, 256, 128); return; }
    b -= 16;
    cvt_w_body(0, b, W3c, B3T + (size_t)4 * 16 * 2048, 256, 128);
}

// fused BN(inline coeffs)+ReLU+cvt -> packed A. grid (40, F/16)
__global__ __launch_bounds__(256) void bn_relu_cvt_kernel(const float* __restrict__ G,
                                                          const float* __restrict__ sums,
                                                          const float* __restrict__ g,
                                                          const float* __restrict__ be,
                                                          us* __restrict__ Ap, int F) {
    const int k16 = blockIdx.y;
    int m = blockIdx.x * 256 + threadIdx.x;
    if (m >= N_NODES) return;
    const float invM = 1.0f / (float)N_NODES;
    float sc[16], sh[16];
    #pragma unroll
    for (int j = 0; j < 16; ++j) {
        int c = k16 * 16 + j;
        float mu = sums[c] * invM;
        float s = g[c] * rsqrtf(sums[F + c] * invM - mu * mu + 1e-5f);
        sc[j] = s;
        sh[j] = be[c] - mu * s;
    }
    const float4* p = (const float4*)(G + (size_t)m * F + k16 * 16);
    float v[16];
    #pragma unroll
    for (int q = 0; q < 4; ++q) {
        float4 t4 = p[q];
        v[q * 4 + 0] = t4.x; v[q * 4 + 1] = t4.y;
        v[q * 4 + 2] = t4.z; v[q * 4 + 3] = t4.w;
    }
    #pragma unroll
    for (int j = 0; j < 16; ++j) v[j] = fmaxf(v[j] * sc[j] + sh[j], 0.f);
    uint4 hi0, hi1, lo0, lo1;
    hi0.x = pack_hi2(v[0], v[1]);  hi0.y = pack_hi2(v[2], v[3]);
    hi0.z = pack_hi2(v[4], v[5]);  hi0.w = pack_hi2(v[6], v[7]);
    hi1.x = pack_hi2(v[8], v[9]);  hi1.y = pack_hi2(v[10], v[11]);
    hi1.z = pack_hi2(v[12], v[13]); hi1.w = pack_hi2(v[14], v[15]);
    lo0.x = pack_lo2(v[0], v[1]);  lo0.y = pack_lo2(v[2], v[3]);
    lo0.z = pack_lo2(v[4], v[5]);  lo0.w = pack_lo2(v[6], v[7]);
    lo1.x = pack_lo2(v[8], v[9]);  lo1.y = pack_lo2(v[10], v[11]);
    lo1.z = pack_lo2(v[12], v[13]); lo1.w = pack_lo2(v[14], v[15]);
    int pa = m >> 7, rr = m & 127;
    int NKT = F >> 4;
    int kt = k16 >> 1, kqb = (k16 & 1) * 2;
    size_t th = ((size_t)pa * NKT + kt) * 4096;
    size_t tl = ((size_t)pa * NKT + (F >> 5) + kt) * 4096;
    *(uint4*)&Ap[th + ((kqb + 0) * 128 + rr) * 8] = hi0;
    *(uint4*)&Ap[th + ((kqb + 1) * 128 + rr) * 8] = hi1;
    *(uint4*)&Ap[tl + ((kqb + 0) * 128 + rr) * 8] = lo0;
    *(uint4*)&Ap[tl + ((kqb + 1) * 128 + rr) * 8] = lo1;
}

// ---------------- bf16x3 MFMA GEMM: 128x64 tile, BK=64, double-buffered ----------------
// 2-phase prefetch (T3 minimum recipe): STAGE(next) issued BEFORE compute(cur);
// single barrier per 64-k step. Staging loads get ~compute-time of head start,
// so the vmcnt(0) drain at the barrier only pays residual latency.

__global__ __launch_bounds__(256, 3) void mfma_gemm_kernel(
        const us* __restrict__ Ap,
        const us* __restrict__ BpT,
        float* __restrict__ C,
        int M, int Ksub, int Nc, int ncb,
        float* __restrict__ sums) {
    __shared__ us As[2][8192];   // 2 bufs x two 32-k tiles (128 rows)
    __shared__ us Bs[2][4096];   // 2 bufs x two 32-k tiles (64 cols)
    const int t = threadIdx.x;
    const int w = t >> 6, l = t & 63;

    int nwg = gridDim.x, bid = blockIdx.x;
    int q = nwg >> 3, r = nwg & 7;
    int xcd = bid & 7, idx = bid >> 3;
    int wgid = (xcd < r ? xcd * (q + 1) : r * (q + 1) + (xcd - r) * q) + idx;
    const int row0 = (wgid / ncb) * 128;
    const int col0 = (wgid % ncb) * 64;

    const int NKTA = Ksub >> 4;
    const int nt = (3 * Ksub) >> 5;     // 32-k tiles (even for all layers)
    const int wr = w >> 1, wc = w & 1;
    const int lr = l & 15, kq = l >> 4;

    const us* Abase = Ap + (size_t)(row0 >> 7) * NKTA * 4096;
    const us* Bbase = BpT + (size_t)(col0 >> 6) * NKTA * 2048;

    // stage one 32-k tile (kt) into buffer `buf`, half-slot kt&1
    auto stage = [&](int buf, int kt) {
        int k0 = kt << 5;
        int kA = (k0 < 2 * Ksub) ? k0 : k0 - 2 * Ksub;   // A blocks: hi, lo, hi
        int kB = (k0 < Ksub)     ? k0 : k0 - Ksub;       // B blocks: hi, hi, lo
        const us* At = Abase + (size_t)(kA >> 5) * 4096;
        const us* Bt = Bbase + (size_t)(kB >> 5) * 2048;
        char* adst = (char*)As[buf] + (kt & 1) * 8192;
        char* bdst = (char*)Bs[buf] + (kt & 1) * 4096;
        gload_lds16(At + (w * 64 + l) * 8,       adst + w * 1024);
        gload_lds16(At + ((w + 4) * 64 + l) * 8, adst + (w + 4) * 1024);
        gload_lds16(Bt + (w * 64 + l) * 8,       bdst + w * 1024);
    };

    floatx4 acc[4][2] = {};

    stage(0, 0); stage(0, 1);
    __syncthreads();                      // vmcnt(0) drain: buf0 ready
    int cur = 0;
    for (int kt2 = 0; kt2 < (nt >> 1); ++kt2) {
        if (kt2 + 1 < (nt >> 1)) {        // prefetch next 64-k step
            stage(cur ^ 1, kt2 * 2 + 2);
            stage(cur ^ 1, kt2 * 2 + 3);
        }
        #pragma unroll
        for (int sub = 0; sub < 2; ++sub) {
            const us* Ac = &As[cur][sub * 4096];
            const us* Bc = &Bs[cur][sub * 2048];
            short8 af[4], bfr[2];
            #pragma unroll
            for (int m = 0; m < 4; ++m)
                af[m] = *(const short8*)&Ac[(kq * 128 + wr * 64 + m * 16 + lr) * 8];
            #pragma unroll
            for (int n = 0; n < 2; ++n)
                bfr[n] = *(const short8*)&Bc[(kq * 64 + wc * 32 + n * 16 + lr) * 8];
            #pragma unroll
            for (int m = 0; m < 4; ++m)
                #pragma unroll
                for (int n = 0; n < 2; ++n)
                    acc[m][n] = __builtin_amdgcn_mfma_f32_16x16x32_bf16(
                        af[m], bfr[n], acc[m][n], 0, 0, 0);
        }
        __syncthreads();                  // next buf ready; cur reads done
        cur ^= 1;
    }

    // C/D layout: col=lane&15, row=(lane>>4)*4+j  [m89/m91]
    #pragma unroll
    for (int m = 0; m < 4; ++m) {
        int rb = row0 + wr * 64 + m * 16 + kq * 4;
        #pragma unroll
        for (int j = 0; j < 4; ++j) {
            int rr = rb + j;
            if (rr < M) {
                #pragma unroll
                for (int n = 0; n < 2; ++n)
                    C[(size_t)rr * Nc + col0 + wc * 32 + n * 16 + lr] = acc[m][n][j];
            }
        }
    }

    if (sums) {
        float s[2] = {0.f, 0.f}, qv[2] = {0.f, 0.f};
        #pragma unroll
        for (int m = 0; m < 4; ++m)
            #pragma unroll
            for (int n = 0; n < 2; ++n)
                #pragma unroll
                for (int j = 0; j < 4; ++j) {
                    float v = acc[m][n][j];
                    s[n] += v; qv[n] += v * v;
                }
        float* red = (float*)As;
        int g8 = wr * 4 + kq;
        #pragma unroll
        for (int n = 0; n < 2; ++n) {
            int c = wc * 32 + n * 16 + lr;
            red[g8 * 128 + c * 2 + 0] = s[n];
            red[g8 * 128 + c * 2 + 1] = qv[n];
        }
        __syncthreads();
        if (t < 128) {
            float tot = 0.f;
            #pragma unroll
            for (int g = 0; g < 8; ++g) tot += red[g * 128 + t];
            int c = t >> 1, e = t & 1;
            atomicAdd(&sums[e * 512 + col0 + c], tot);
        }
    }
}

// ---------------- graph propagation (float4 gathers, max TLP; verified r6) ----------------

__global__ __launch_bounds__(256) void prop_l2_kernel(const float* __restrict__ G2,
                                                      const int* __restrict__ rowptr,
                                                      const int* __restrict__ csr_s,
                                                      const float* __restrict__ csr_w,
                                                      float* __restrict__ out2) {
    const int g = threadIdx.x >> 6, lane = threadIdx.x & 63;
    const int n = blockIdx.x * 4 + g;
    const int f4 = lane * 4;
    float4 acc = {0.f, 0.f, 0.f, 0.f};
    int e = rowptr[n];
    const int e1 = rowptr[n + 1];
    for (; e + 1 < e1; e += 2) {
        int s0 = csr_s[e], s1 = csr_s[e + 1];
        float w0 = csr_w[e], w1 = csr_w[e + 1];
        float4 a = *(const float4*)&G2[(size_t)s0 * 512 + 256 + f4];
        float4 b = *(const float4*)&G2[(size_t)s1 * 512 + 256 + f4];
        acc.x += w0 * a.x + w1 * b.x; acc.y += w0 * a.y + w1 * b.y;
        acc.z += w0 * a.z + w1 * b.z; acc.w += w0 * a.w + w1 * b.w;
    }
    if (e < e1) {
        float w0 = csr_w[e];
        float4 a = *(const float4*)&G2[(size_t)csr_s[e] * 512 + 256 + f4];
        acc.x += w0 * a.x; acc.y += w0 * a.y; acc.z += w0 * a.z; acc.w += w0 * a.w;
    }
    float4 base = *(const float4*)&G2[(size_t)n * 512 + f4];
    acc.x += base.x; acc.y += base.y; acc.z += base.z; acc.w += base.w;
    *(float4*)&out2[(size_t)n * 256 + f4] = acc;
}

__global__ __launch_bounds__(256) void bn_stats256_kernel(const float* __restrict__ h,
                                                          float* __restrict__ sums) {
    const int t = threadIdx.x;
    int r0 = blockIdx.x * 20, r1 = min(r0 + 20, N_NODES);
    float s = 0.f, q = 0.f;
    for (int r = r0; r < r1; ++r) {
        float v = h[(size_t)r * 256 + t];
        s += v; q += v * v;
    }
    atomicAdd(&sums[t], s);
    atomicAdd(&sums[256 + t], q);
}

__global__ __launch_bounds__(256) void prop3a_kernel(const float* __restrict__ G3,
                                                     const int* __restrict__ rowptr,
                                                     const int* __restrict__ csr_s,
                                                     const float* __restrict__ csr_w,
                                                     float* __restrict__ T) {
    const int g = threadIdx.x >> 5, lane = threadIdx.x & 31;
    const int n = blockIdx.x * 8 + g;
    const int f4 = lane * 4;
    float4 acc = {0.f, 0.f, 0.f, 0.f};
    int e = rowptr[n];
    const int e1 = rowptr[n + 1];
    for (; e + 1 < e1; e += 2) {
        int s0 = csr_s[e], s1 = csr_s[e + 1];
        float w0 = csr_w[e], w1 = csr_w[e + 1];
        float4 a = *(const float4*)&G3[(size_t)s0 * 384 + 256 + f4];
        float4 b = *(const float4*)&G3[(size_t)s1 * 384 + 256 + f4];
        acc.x += w0 * a.x + w1 * b.x; acc.y += w0 * a.y + w1 * b.y;
        acc.z += w0 * a.z + w1 * b.z; acc.w += w0 * a.w + w1 * b.w;
    }
    if (e < e1) {
        float w0 = csr_w[e];
        float4 a = *(const float4*)&G3[(size_t)csr_s[e] * 384 + 256 + f4];
        acc.x += w0 * a.x; acc.y += w0 * a.y; acc.z += w0 * a.z; acc.w += w0 * a.w;
    }
    *(float4*)&T[(size_t)n * 128 + f4] = acc;
}

__global__ __launch_bounds__(256) void prop3b_combine_kernel(const float* __restrict__ G3,
                                                             const float* __restrict__ T,
                                                             const int* __restrict__ rowptr,
                                                             const int* __restrict__ csr_s,
                                                             const float* __restrict__ csr_w,
                                                             float* __restrict__ Fbuf,
                                                             float* __restrict__ sums) {
    __shared__ float red_s[8][128];
    __shared__ float red_q[8][128];
    const int g = threadIdx.x >> 5, lane = threadIdx.x & 31;
    const int n = blockIdx.x * 8 + g;
    const int f4 = lane * 4;
    float4 acc = {0.f, 0.f, 0.f, 0.f};
    int e = rowptr[n];
    const int e1 = rowptr[n + 1];
    for (; e < e1; ++e) {
        int s = csr_s[e];
        float w0 = csr_w[e];
        float4 a = *(const float4*)&G3[(size_t)s * 384 + 128 + f4];
        float4 b = *(const float4*)&T[(size_t)s * 128 + f4];
        acc.x += w0 * (a.x + 2.f * b.x); acc.y += w0 * (a.y + 2.f * b.y);
        acc.z += w0 * (a.z + 2.f * b.z); acc.w += w0 * (a.w + 2.f * b.w);
    }
    float4 p = *(const float4*)&G3[(size_t)n * 384 + f4];
    float4 r = *(const float4*)&G3[(size_t)n * 384 + 256 + f4];
    float4 v;
    v.x = p.x - r.x + acc.x; v.y = p.y - r.y + acc.y;
    v.z = p.z - r.z + acc.z; v.w = p.w - r.w + acc.w;
    *(float4*)&Fbuf[(size_t)n * 128 + f4] = v;
    red_s[g][f4 + 0] = v.x; red_s[g][f4 + 1] = v.y;
    red_s[g][f4 + 2] = v.z; red_s[g][f4 + 3] = v.w;
    red_q[g][f4 + 0] = v.x * v.x; red_q[g][f4 + 1] = v.y * v.y;
    red_q[g][f4 + 2] = v.z * v.z; red_q[g][f4 + 3] = v.w * v.w;
    __syncthreads();
    const int t = threadIdx.x;
    if (t < 128) {
        float s = 0.f, q = 0.f;
        #pragma unroll
        for (int gg = 0; gg < 8; ++gg) { s += red_s[gg][t]; q += red_q[gg][t]; }
        atomicAdd(&sums[t], s);
        atomicAdd(&sums[128 + t], q);
    }
}

// ---------------- fused BN3 (inline coeffs) + FC(128->6) + log_softmax ----------------

__global__ __launch_bounds__(256) void final_kernel(const float* __restrict__ h,
                                                    const float* __restrict__ sums,
                                                    const float* __restrict__ g3,
                                                    const float* __restrict__ be3,
                                                    const float* __restrict__ fcW,
                                                    const float* __restrict__ fcb,
                                                    float* __restrict__ out) {
    const int t = threadIdx.x, lane = t & 63, wid = t >> 6;
    const int r = blockIdx.x * 4 + wid;
    if (r >= N_NODES) return;
    const float invM = 1.0f / (float)N_NODES;
    float v[6] = {0.f, 0.f, 0.f, 0.f, 0.f, 0.f};
    #pragma unroll
    for (int kk = 0; kk < 2; ++kk) {
        int k = lane + kk * 64;
        float mu = sums[k] * invM;
        float sc = g3[k] * rsqrtf(sums[128 + k] * invM - mu * mu + 1e-5f);
        float sh = be3[k] - mu * sc;
        float x = h[(size_t)r * 128 + k] * sc + sh;
        #pragma unroll
        for (int j = 0; j < 6; ++j) v[j] += x * fcW[k * 6 + j];
    }
    #pragma unroll
    for (int j = 0; j < 6; ++j)
        #pragma unroll
        for (int off = 32; off > 0; off >>= 1) v[j] += __shfl_down(v[j], off);
    if (lane == 0) {
        #pragma unroll
        for (int j = 0; j < 6; ++j) v[j] += fcb[j];
        float m = v[0];
        #pragma unroll
        for (int j = 1; j < 6; ++j) m = fmaxf(m, v[j]);
        float s = 0.f;
        #pragma unroll
        for (int j = 0; j < 6; ++j) s += expf(v[j] - m);
        float l = m + logf(s);
        #pragma unroll
        for (int j = 0; j < 6; ++j) out[r * 6 + j] = v[j] - l;
    }
}

// ---------------- launch ----------------

extern "C" void kernel_launch(void* const* d_in, const int* in_sizes, int n_in,
                              void* d_out, int out_size, void* d_ws, size_t ws_size,
                              hipStream_t stream) {
    (void)in_sizes; (void)n_in; (void)out_size; (void)ws_size;
    const float* x   = (const float*)d_in[0];
    const int*   ei  = (const int*)d_in[1];
    const float* ea  = (const float*)d_in[2];
    const float* W1  = (const float*)d_in[3];
    // b1/b2/b3 (d_in[4],[9],[15]) cancel under training-mode BN
    const float* g1  = (const float*)d_in[5];
    const float* be1 = (const float*)d_in[6];
    const float* W2a = (const float*)d_in[7];
    const float* W2b = (const float*)d_in[8];
    const float* g2  = (const float*)d_in[10];
    const float* be2 = (const float*)d_in[11];
    const float* W3a = (const float*)d_in[12];
    const float* W3b = (const float*)d_in[13];
    const float* W3c = (const float*)d_in[14];
    const float* g3  = (const float*)d_in[16];
    const float* be3 = (const float*)d_in[17];
    const float* fcW = (const float*)d_in[18];
    const float* fcb = (const float*)d_in[19];
    float* out = (float*)d_out;

    const int* src = ei;
    const int* dst = ei + N_EDGES;

    char* w = (char*)d_ws;
    size_t off = 0;
    auto alloc = [&](size_t bytes) -> void* {
        void* p = w + off;
        off += (bytes + 4095) & ~(size_t)4095;
        return p;
    };
    // zeroed region first
    float* deg    = (float*)alloc(N_NODES * 4);
    int*   cnt    = (int*)  alloc(N_NODES * 4);
    int*   fillc  = (int*)  alloc(N_NODES * 4);
    float* sums1  = (float*)alloc(1024 * 4);
    float* sums2  = (float*)alloc(1024 * 4);
    float* sums3  = (float*)alloc(1024 * 4);
    size_t zero_bytes = off;
    float* dis    = (float*)alloc(N_NODES * 4);
    int*   rowptr = (int*)  alloc((N_NODES + 1) * 4);
    int*   csr_s  = (int*)  alloc(N_EDGES * 4);
    float* csr_w  = (float*)alloc(N_EDGES * 4);
    us* B1T = (us*)alloc((size_t)512 * 1536 * 2);
    us* B2T = (us*)alloc((size_t)512 * 1024 * 2);
    us* B3T = (us*)alloc((size_t)384 * 512 * 2);
    // aliased big slots
    us* slotA = (us*)alloc((size_t)MPAD * 1536 * 2);          // A'1/A'2/A'3 (packed)
    float* slotG = (float*)alloc((size_t)N_NODES * 512 * 4);  // G1/G2/G3
    float* slotC = (float*)alloc((size_t)N_NODES * 256 * 4);  // out2 ; then T
    float* bufF  = (float*)alloc((size_t)N_NODES * 128 * 4);

    us* A1 = slotA;
    us* A2 = slotA;
    us* A3 = slotA;
    float* G1 = slotG;
    float* G2 = slotG;
    float* G3 = slotG;
    float* out2 = slotC;
    float* bufT = slotC;     // overwrites out2 after it is consumed

    hipMemsetAsync(d_ws, 0, zero_bytes, stream);

    // graph preprocessing -> dst-CSR with normalized weights
    deg_kernel<<<N_EDGES / 256, 256, 0, stream>>>(src, dst, ea, deg, cnt);
    dis_scan_kernel<<<40, 1024, 0, stream>>>(deg, cnt, dis, rowptr);
    fill_kernel<<<N_EDGES / 256, 256, 0, stream>>>(src, dst, ea, dis, rowptr, fillc,
                                                   csr_s, csr_w);

    // all fp32->bf16 hi/lo packed conversions in one dispatch
    cvt_all_kernel<<<2128, 256, 0, stream>>>(x, A1, W1, B1T, W2a, W2b, B2T,
                                             W3a, W3b, W3c, B3T);

    // ---- layer 1: G1 = x @ W1 (bf16x3) + fused BN stats; BN+ReLU+cvt -> A'2 ----
    mfma_gemm_kernel<<<632, 256, 0, stream>>>(A1, B1T, G1, N_NODES, 768, 512, 8, sums1);
    bn_relu_cvt_kernel<<<dim3(40, 32), 256, 0, stream>>>(G1, sums1, g1, be1, A2, 512);

    // ---- layer 2: G2 = h1 @ [W2a|W2b]; out2 = y0 + P y1; stats; cvt -> A'3 ----
    mfma_gemm_kernel<<<632, 256, 0, stream>>>(A2, B2T, G2, N_NODES, 512, 512, 8, nullptr);
    prop_l2_kernel<<<2500, 256, 0, stream>>>(G2, rowptr, csr_s, csr_w, out2);
    bn_stats256_kernel<<<500, 256, 0, stream>>>(out2, sums2);
    bn_relu_cvt_kernel<<<dim3(40, 16), 256, 0, stream>>>(out2, sums2, g2, be2, A3, 256);

    // ---- layer 3: G3 = h2 @ [W3a|W3b|W3c] = [f0|g1|g2] ----
    mfma_gemm_kernel<<<474, 256, 0, stream>>>(A3, B3T, G3, N_NODES, 256, 384, 6, nullptr);
    // T = P g2 ; U = P(g1 + 2T) ; out3 = f0 - g2 + U  (+ fused BN stats)
    prop3a_kernel<<<1250, 256, 0, stream>>>(G3, rowptr, csr_s, csr_w, bufT);
    prop3b_combine_kernel<<<1250, 256, 0, stream>>>(G3, bufT, rowptr, csr_s, csr_w,
                                                    bufF, sums3);

    // ---- BN3 (inline coeffs) + FC + log_softmax fused ----
    final_kernel<<<2500, 256, 0, stream>>>(bufF, sums3, g3, be3, fcW, fcb, out);
}

// Round 10
// 348.354 us; speedup vs baseline: 1.3978x; 1.0253x over previous
//
#include <hip/hip_runtime.h>
#include <hip/hip_bf16.h>
#include <cstdint>

#define N_NODES 10000
#define N_EDGES 160000
#define MPAD    10112   // 79 * 128

typedef __attribute__((ext_vector_type(8))) short short8;
typedef __attribute__((ext_vector_type(4))) float floatx4;
typedef unsigned short us;

// ---------------- helpers ----------------

__device__ __forceinline__ us bf16_rn(float f) {
    union { float f; unsigned u; } c{f};
    unsigned r = c.u + 0x7FFF + ((c.u >> 16) & 1);   // round-to-nearest-even
    return (us)(r >> 16);
}
__device__ __forceinline__ float bf16_to_f(us h) {
    union { unsigned u; float f; } c{(unsigned)h << 16};
    return c.f;
}
__device__ __forceinline__ unsigned pack_hi2(float a, float b) {
    return (unsigned)bf16_rn(a) | ((unsigned)bf16_rn(b) << 16);
}
__device__ __forceinline__ unsigned pack_lo2(float a, float b) {
    float ra = a - bf16_to_f(bf16_rn(a));
    float rb = b - bf16_to_f(bf16_rn(b));
    return (unsigned)bf16_rn(ra) | ((unsigned)bf16_rn(rb) << 16);
}

__device__ __forceinline__ void gload_lds16(const void* g, void* l) {
    __builtin_amdgcn_global_load_lds(
        (const __attribute__((address_space(1))) unsigned int*)g,
        (__attribute__((address_space(3))) unsigned int*)l, 16, 0, 0);
}

// ================= tile-packed bf16 layouts (verified round 5) =================
// A_packed: per 128-row panel pa, per 32-k tile kt: 4096 elems as
//   elem((kq*128 + rr)*8 + e); width axis = [hi | lo] concat (2K).
// B_packed: per 64-col panel pb, per 32-k tile: 2048 elems, (kq*64 + c)*8 + e.

// ---------------- edge preprocessing ----------------

__global__ void deg_kernel(const int* __restrict__ src, const int* __restrict__ dst,
                           const float* __restrict__ ew,
                           float* __restrict__ deg, int* __restrict__ cnt) {
    int e = blockIdx.x * blockDim.x + threadIdx.x;
    if (e >= N_EDGES) return;
    atomicAdd(&deg[src[e]], ew[e]);
    atomicAdd(&cnt[dst[e]], 1);
}

// block 0: exclusive scan cnt -> rowptr ; blocks 1..39: dis = rsqrt(deg)
__global__ __launch_bounds__(1024) void dis_scan_kernel(const float* __restrict__ deg,
                                                        const int* __restrict__ cnt,
                                                        float* __restrict__ dis,
                                                        int* __restrict__ rowptr) {
    const int t = threadIdx.x;
    if (blockIdx.x != 0) {
        int n = (blockIdx.x - 1) * 1024 + t;
        if (n < N_NODES) {
            float d = deg[n];
            dis[n] = d > 0.f ? rsqrtf(d) : 0.f;
        }
        return;
    }
    __shared__ int wsum[16];
    const int lane = t & 63, wid = t >> 6;
    int carry = 0;
    for (int base = 0; base < N_NODES; base += 1024) {
        int i = base + t;
        int v = (i < N_NODES) ? cnt[i] : 0;
        int s = v;
        #pragma unroll
        for (int off = 1; off < 64; off <<= 1) {
            int u = __shfl_up(s, off);
            if (lane >= off) s += u;
        }
        if (lane == 63) wsum[wid] = s;
        __syncthreads();
        int woff = 0, tot = 0;
        for (int ww = 0; ww < 16; ++ww) {
            int xv = wsum[ww];
            if (ww < wid) woff += xv;
            tot += xv;
        }
        if (i < N_NODES) rowptr[i + 1] = carry + woff + s;
        carry += tot;
        __syncthreads();
    }
    if (t == 0) rowptr[0] = 0;
}

__global__ void fill_kernel(const int* __restrict__ src, const int* __restrict__ dst,
                            const float* __restrict__ ew, const float* __restrict__ dis,
                            const int* __restrict__ rowptr, int* __restrict__ fill,
                            int* __restrict__ csr_src, float* __restrict__ csr_w) {
    int e = blockIdx.x * blockDim.x + threadIdx.x;
    if (e >= N_EDGES) return;
    int s = src[e], d = dst[e];
    int pos = rowptr[d] + atomicAdd(&fill[d], 1);
    csr_src[pos] = s;
    csr_w[pos] = -dis[s] * ew[e] * dis[d];
}

// ---------------- packed conversions ----------------

__device__ __forceinline__ void cvt_x_body(int bx, int k16, const float* __restrict__ x,
                                           us* __restrict__ Ap) {
    int m = bx * 256 + threadIdx.x;
    if (m >= N_NODES) return;
    const float4* p = (const float4*)(x + (size_t)m * 768 + k16 * 16);
    float4 v0 = p[0], v1 = p[1], v2 = p[2], v3 = p[3];
    uint4 hi0, hi1, lo0, lo1;
    hi0.x = pack_hi2(v0.x, v0.y); hi0.y = pack_hi2(v0.z, v0.w);
    hi0.z = pack_hi2(v1.x, v1.y); hi0.w = pack_hi2(v1.z, v1.w);
    hi1.x = pack_hi2(v2.x, v2.y); hi1.y = pack_hi2(v2.z, v2.w);
    hi1.z = pack_hi2(v3.x, v3.y); hi1.w = pack_hi2(v3.z, v3.w);
    lo0.x = pack_lo2(v0.x, v0.y); lo0.y = pack_lo2(v0.z, v0.w);
    lo0.z = pack_lo2(v1.x, v1.y); lo0.w = pack_lo2(v1.z, v1.w);
    lo1.x = pack_lo2(v2.x, v2.y); lo1.y = pack_lo2(v2.z, v2.w);
    lo1.z = pack_lo2(v3.x, v3.y); lo1.w = pack_lo2(v3.z, v3.w);
    int pa = m >> 7, rr = m & 127;
    int kt = k16 >> 1, kqb = (k16 & 1) * 2;
    size_t th = ((size_t)pa * 48 + kt) * 4096;
    size_t tl = ((size_t)pa * 48 + 24 + kt) * 4096;
    *(uint4*)&Ap[th + ((kqb + 0) * 128 + rr) * 8] = hi0;
    *(uint4*)&Ap[th + ((kqb + 1) * 128 + rr) * 8] = hi1;
    *(uint4*)&Ap[tl + ((kqb + 0) * 128 + rr) * 8] = lo0;
    *(uint4*)&Ap[tl + ((kqb + 1) * 128 + rr) * 8] = lo1;
}

__device__ __forceinline__ void cvt_w_body(int bx, int k16, const float* __restrict__ W,
                                           us* __restrict__ Bp, int K, int N) {
    int n = bx * 256 + threadIdx.x;
    if (n >= N) return;
    float v[16];
    #pragma unroll
    for (int j = 0; j < 16; ++j) v[j] = W[(size_t)(k16 * 16 + j) * N + n];
    uint4 hi0, hi1, lo0, lo1;
    hi0.x = pack_hi2(v[0], v[1]);  hi0.y = pack_hi2(v[2], v[3]);
    hi0.z = pack_hi2(v[4], v[5]);  hi0.w = pack_hi2(v[6], v[7]);
    hi1.x = pack_hi2(v[8], v[9]);  hi1.y = pack_hi2(v[10], v[11]);
    hi1.z = pack_hi2(v[12], v[13]); hi1.w = pack_hi2(v[14], v[15]);
    lo0.x = pack_lo2(v[0], v[1]);  lo0.y = pack_lo2(v[2], v[3]);
    lo0.z = pack_lo2(v[4], v[5]);  lo0.w = pack_lo2(v[6], v[7]);
    lo1.x = pack_lo2(v[8], v[9]);  lo1.y = pack_lo2(v[10], v[11]);
    lo1.z = pack_lo2(v[12], v[13]); lo1.w = pack_lo2(v[14], v[15]);
    int pb = n >> 6, c = n & 63;
    int NKTB = K >> 4;
    int kt = k16 >> 1, kqb = (k16 & 1) * 2;
    size_t th = ((size_t)pb * NKTB + kt) * 2048;
    size_t tl = ((size_t)pb * NKTB + (K >> 5) + kt) * 2048;
    *(uint4*)&Bp[th + ((kqb + 0) * 64 + c) * 8] = hi0;
    *(uint4*)&Bp[th + ((kqb + 1) * 64 + c) * 8] = hi1;
    *(uint4*)&Bp[tl + ((kqb + 0) * 64 + c) * 8] = lo0;
    *(uint4*)&Bp[tl + ((kqb + 1) * 64 + c) * 8] = lo1;
}

__global__ __launch_bounds__(256) void cvt_all_kernel(const float* __restrict__ x,
                                                      us* __restrict__ A1,
                                                      const float* __restrict__ W1,
                                                      us* __restrict__ B1T,
                                                      const float* __restrict__ W2a,
                                                      const float* __restrict__ W2b,
                                                      us* __restrict__ B2T,
                                                      const float* __restrict__ W3a,
                                                      const float* __restrict__ W3b,
                                                      const float* __restrict__ W3c,
                                                      us* __restrict__ B3T) {
    int b = blockIdx.x;
    if (b < 1920) { cvt_x_body(b % 40, b / 40, x, A1); return; }
    b -= 1920;
    if (b < 96)  { cvt_w_body(b & 1, b >> 1, W1, B1T, 768, 512); return; }
    b -= 96;
    if (b < 32)  { cvt_w_body(0, b, W2a, B2T, 512, 256); return; }
    b -= 32;
    if (b < 32)  { cvt_w_body(0, b, W2b, B2T + (size_t)4 * 32 * 2048, 512, 256); return; }
    b -= 32;
    if (b < 16)  { cvt_w_body(0, b, W3a, B3T, 256, 128); return; }
    b -= 16;
    if (b < 16)  { cvt_w_body(0, b, W3b, B3T + (size_t)2 * 16 * 2048, 256, 128); return; }
    b -= 16;
    cvt_w_body(0, b, W3c, B3T + (size_t)4 * 16 * 2048, 256, 128);
}

// fused BN(inline coeffs)+ReLU+cvt -> packed A. grid (40, F/16)
__global__ __launch_bounds__(256) void bn_relu_cvt_kernel(const float* __restrict__ G,
                                                          const float* __restrict__ sums,
                                                          const float* __restrict__ g,
                                                          const float* __restrict__ be,
                                                          us* __restrict__ Ap, int F) {
    const int k16 = blockIdx.y;
    int m = blockIdx.x * 256 + threadIdx.x;
    if (m >= N_NODES) return;
    const float invM = 1.0f / (float)N_NODES;
    float sc[16], sh[16];
    #pragma unroll
    for (int j = 0; j < 16; ++j) {
        int c = k16 * 16 + j;
        float mu = sums[c] * invM;
        float s = g[c] * rsqrtf(sums[F + c] * invM - mu * mu + 1e-5f);
        sc[j] = s;
        sh[j] = be[c] - mu * s;
    }
    const float4* p = (const float4*)(G + (size_t)m * F + k16 * 16);
    float v[16];
    #pragma unroll
    for (int q = 0; q < 4; ++q) {
        float4 t4 = p[q];
        v[q * 4 + 0] = t4.x; v[q * 4 + 1] = t4.y;
        v[q * 4 + 2] = t4.z; v[q * 4 + 3] = t4.w;
    }
    #pragma unroll
    for (int j = 0; j < 16; ++j) v[j] = fmaxf(v[j] * sc[j] + sh[j], 0.f);
    uint4 hi0, hi1, lo0, lo1;
    hi0.x = pack_hi2(v[0], v[1]);  hi0.y = pack_hi2(v[2], v[3]);
    hi0.z = pack_hi2(v[4], v[5]);  hi0.w = pack_hi2(v[6], v[7]);
    hi1.x = pack_hi2(v[8], v[9]);  hi1.y = pack_hi2(v[10], v[11]);
    hi1.z = pack_hi2(v[12], v[13]); hi1.w = pack_hi2(v[14], v[15]);
    lo0.x = pack_lo2(v[0], v[1]);  lo0.y = pack_lo2(v[2], v[3]);
    lo0.z = pack_lo2(v[4], v[5]);  lo0.w = pack_lo2(v[6], v[7]);
    lo1.x = pack_lo2(v[8], v[9]);  lo1.y = pack_lo2(v[10], v[11]);
    lo1.z = pack_lo2(v[12], v[13]); lo1.w = pack_lo2(v[14], v[15]);
    int pa = m >> 7, rr = m & 127;
    int NKT = F >> 4;
    int kt = k16 >> 1, kqb = (k16 & 1) * 2;
    size_t th = ((size_t)pa * NKT + kt) * 4096;
    size_t tl = ((size_t)pa * NKT + (F >> 5) + kt) * 4096;
    *(uint4*)&Ap[th + ((kqb + 0) * 128 + rr) * 8] = hi0;
    *(uint4*)&Ap[th + ((kqb + 1) * 128 + rr) * 8] = hi1;
    *(uint4*)&Ap[tl + ((kqb + 0) * 128 + rr) * 8] = lo0;
    *(uint4*)&Ap[tl + ((kqb + 1) * 128 + rr) * 8] = lo1;
}

// ---------------- bf16x3 MFMA GEMM: 128x64 tile, BK=64, double-buffered (r9 verified) ----------------

__global__ __launch_bounds__(256, 3) void mfma_gemm_kernel(
        const us* __restrict__ Ap,
        const us* __restrict__ BpT,
        float* __restrict__ C,
        int M, int Ksub, int Nc, int ncb,
        float* __restrict__ sums) {
    __shared__ us As[2][8192];   // 2 bufs x two 32-k tiles (128 rows)
    __shared__ us Bs[2][4096];   // 2 bufs x two 32-k tiles (64 cols)
    const int t = threadIdx.x;
    const int w = t >> 6, l = t & 63;

    int nwg = gridDim.x, bid = blockIdx.x;
    int q = nwg >> 3, r = nwg & 7;
    int xcd = bid & 7, idx = bid >> 3;
    int wgid = (xcd < r ? xcd * (q + 1) : r * (q + 1) + (xcd - r) * q) + idx;
    const int row0 = (wgid / ncb) * 128;
    const int col0 = (wgid % ncb) * 64;

    const int NKTA = Ksub >> 4;
    const int nt = (3 * Ksub) >> 5;     // 32-k tiles (even for all layers)
    const int wr = w >> 1, wc = w & 1;
    const int lr = l & 15, kq = l >> 4;

    const us* Abase = Ap + (size_t)(row0 >> 7) * NKTA * 4096;
    const us* Bbase = BpT + (size_t)(col0 >> 6) * NKTA * 2048;

    // stage one 32-k tile (kt) into buffer `buf`, half-slot kt&1
    auto stage = [&](int buf, int kt) {
        int k0 = kt << 5;
        int kA = (k0 < 2 * Ksub) ? k0 : k0 - 2 * Ksub;   // A blocks: hi, lo, hi
        int kB = (k0 < Ksub)     ? k0 : k0 - Ksub;       // B blocks: hi, hi, lo
        const us* At = Abase + (size_t)(kA >> 5) * 4096;
        const us* Bt = Bbase + (size_t)(kB >> 5) * 2048;
        char* adst = (char*)As[buf] + (kt & 1) * 8192;
        char* bdst = (char*)Bs[buf] + (kt & 1) * 4096;
        gload_lds16(At + (w * 64 + l) * 8,       adst + w * 1024);
        gload_lds16(At + ((w + 4) * 64 + l) * 8, adst + (w + 4) * 1024);
        gload_lds16(Bt + (w * 64 + l) * 8,       bdst + w * 1024);
    };

    floatx4 acc[4][2] = {};

    stage(0, 0); stage(0, 1);
    __syncthreads();                      // vmcnt(0) drain: buf0 ready
    int cur = 0;
    for (int kt2 = 0; kt2 < (nt >> 1); ++kt2) {
        if (kt2 + 1 < (nt >> 1)) {        // prefetch next 64-k step
            stage(cur ^ 1, kt2 * 2 + 2);
            stage(cur ^ 1, kt2 * 2 + 3);
        }
        #pragma unroll
        for (int sub = 0; sub < 2; ++sub) {
            const us* Ac = &As[cur][sub * 4096];
            const us* Bc = &Bs[cur][sub * 2048];
            short8 af[4], bfr[2];
            #pragma unroll
            for (int m = 0; m < 4; ++m)
                af[m] = *(const short8*)&Ac[(kq * 128 + wr * 64 + m * 16 + lr) * 8];
            #pragma unroll
            for (int n = 0; n < 2; ++n)
                bfr[n] = *(const short8*)&Bc[(kq * 64 + wc * 32 + n * 16 + lr) * 8];
            #pragma unroll
            for (int m = 0; m < 4; ++m)
                #pragma unroll
                for (int n = 0; n < 2; ++n)
                    acc[m][n] = __builtin_amdgcn_mfma_f32_16x16x32_bf16(
                        af[m], bfr[n], acc[m][n], 0, 0, 0);
        }
        __syncthreads();                  // next buf ready; cur reads done
        cur ^= 1;
    }

    // C/D layout: col=lane&15, row=(lane>>4)*4+j  [m89/m91]
    #pragma unroll
    for (int m = 0; m < 4; ++m) {
        int rb = row0 + wr * 64 + m * 16 + kq * 4;
        #pragma unroll
        for (int j = 0; j < 4; ++j) {
            int rr = rb + j;
            if (rr < M) {
                #pragma unroll
                for (int n = 0; n < 2; ++n)
                    C[(size_t)rr * Nc + col0 + wc * 32 + n * 16 + lr] = acc[m][n][j];
            }
        }
    }

    if (sums) {
        float s[2] = {0.f, 0.f}, qv[2] = {0.f, 0.f};
        #pragma unroll
        for (int m = 0; m < 4; ++m)
            #pragma unroll
            for (int n = 0; n < 2; ++n)
                #pragma unroll
                for (int j = 0; j < 4; ++j) {
                    float v = acc[m][n][j];
                    s[n] += v; qv[n] += v * v;
                }
        float* red = (float*)As;
        int g8 = wr * 4 + kq;
        #pragma unroll
        for (int n = 0; n < 2; ++n) {
            int c = wc * 32 + n * 16 + lr;
            red[g8 * 128 + c * 2 + 0] = s[n];
            red[g8 * 128 + c * 2 + 1] = qv[n];
        }
        __syncthreads();
        if (t < 128) {
            float tot = 0.f;
            #pragma unroll
            for (int g = 0; g < 8; ++g) tot += red[g * 128 + t];
            int c = t >> 1, e = t & 1;
            atomicAdd(&sums[e * 512 + col0 + c], tot);
        }
    }
}

// ---------------- graph propagation (float4 gathers, max TLP; verified r6/r9) ----------------

__global__ __launch_bounds__(256) void prop_l2_kernel(const float* __restrict__ G2,
                                                      const int* __restrict__ rowptr,
                                                      const int* __restrict__ csr_s,
                                                      const float* __restrict__ csr_w,
                                                      float* __restrict__ out2) {
    const int g = threadIdx.x >> 6, lane = threadIdx.x & 63;
    const int n = blockIdx.x * 4 + g;
    const int f4 = lane * 4;
    float4 acc = {0.f, 0.f, 0.f, 0.f};
    int e = rowptr[n];
    const int e1 = rowptr[n + 1];
    for (; e + 1 < e1; e += 2) {
        int s0 = csr_s[e], s1 = csr_s[e + 1];
        float w0 = csr_w[e], w1 = csr_w[e + 1];
        float4 a = *(const float4*)&G2[(size_t)s0 * 512 + 256 + f4];
        float4 b = *(const float4*)&G2[(size_t)s1 * 512 + 256 + f4];
        acc.x += w0 * a.x + w1 * b.x; acc.y += w0 * a.y + w1 * b.y;
        acc.z += w0 * a.z + w1 * b.z; acc.w += w0 * a.w + w1 * b.w;
    }
    if (e < e1) {
        float w0 = csr_w[e];
        float4 a = *(const float4*)&G2[(size_t)csr_s[e] * 512 + 256 + f4];
        acc.x += w0 * a.x; acc.y += w0 * a.y; acc.z += w0 * a.z; acc.w += w0 * a.w;
    }
    float4 base = *(const float4*)&G2[(size_t)n * 512 + f4];
    acc.x += base.x; acc.y += base.y; acc.z += base.z; acc.w += base.w;
    *(float4*)&out2[(size_t)n * 256 + f4] = acc;
}

__global__ __launch_bounds__(256) void bn_stats256_kernel(const float* __restrict__ h,
                                                          float* __restrict__ sums) {
    const int t = threadIdx.x;
    int r0 = blockIdx.x * 20, r1 = min(r0 + 20, N_NODES);
    float s = 0.f, q = 0.f;
    for (int r = r0; r < r1; ++r) {
        float v = h[(size_t)r * 256 + t];
        s += v; q += v * v;
    }
    atomicAdd(&sums[t], s);
    atomicAdd(&sums[256 + t], q);
}

// Tc[n] = G3[n][128..256) + 2 * sum_e w * G3[src][256+f]   (fold g1 + 2T here:
// prop3b then gathers ONE row per edge instead of two — halves gather volume)
__global__ __launch_bounds__(256) void prop3a_kernel(const float* __restrict__ G3,
                                                     const int* __restrict__ rowptr,
                                                     const int* __restrict__ csr_s,
                                                     const float* __restrict__ csr_w,
                                                     float* __restrict__ Tc) {
    const int g = threadIdx.x >> 5, lane = threadIdx.x & 31;
    const int n = blockIdx.x * 8 + g;
    const int f4 = lane * 4;
    float4 acc = {0.f, 0.f, 0.f, 0.f};
    int e = rowptr[n];
    const int e1 = rowptr[n + 1];
    for (; e + 1 < e1; e += 2) {
        int s0 = csr_s[e], s1 = csr_s[e + 1];
        float w0 = csr_w[e], w1 = csr_w[e + 1];
        float4 a = *(const float4*)&G3[(size_t)s0 * 384 + 256 + f4];
        float4 b = *(const float4*)&G3[(size_t)s1 * 384 + 256 + f4];
        acc.x += w0 * a.x + w1 * b.x; acc.y += w0 * a.y + w1 * b.y;
        acc.z += w0 * a.z + w1 * b.z; acc.w += w0 * a.w + w1 * b.w;
    }
    if (e < e1) {
        float w0 = csr_w[e];
        float4 a = *(const float4*)&G3[(size_t)csr_s[e] * 384 + 256 + f4];
        acc.x += w0 * a.x; acc.y += w0 * a.y; acc.z += w0 * a.z; acc.w += w0 * a.w;
    }
    float4 g1r = *(const float4*)&G3[(size_t)n * 384 + 128 + f4];  // own row, coalesced
    float4 v;
    v.x = g1r.x + 2.f * acc.x; v.y = g1r.y + 2.f * acc.y;
    v.z = g1r.z + 2.f * acc.z; v.w = g1r.w + 2.f * acc.w;
    *(float4*)&Tc[(size_t)n * 128 + f4] = v;
}

// out3 = f0 - g2 + P Tc ; fused BN stats. Single-row gather per edge.
__global__ __launch_bounds__(256) void prop3b_combine_kernel(const float* __restrict__ G3,
                                                             const float* __restrict__ Tc,
                                                             const int* __restrict__ rowptr,
                                                             const int* __restrict__ csr_s,
                                                             const float* __restrict__ csr_w,
                                                             float* __restrict__ Fbuf,
                                                             float* __restrict__ sums) {
    __shared__ float red_s[8][128];
    __shared__ float red_q[8][128];
    const int g = threadIdx.x >> 5, lane = threadIdx.x & 31;
    const int n = blockIdx.x * 8 + g;
    const int f4 = lane * 4;
    float4 acc = {0.f, 0.f, 0.f, 0.f};
    int e = rowptr[n];
    const int e1 = rowptr[n + 1];
    for (; e + 1 < e1; e += 2) {
        int s0 = csr_s[e], s1 = csr_s[e + 1];
        float w0 = csr_w[e], w1 = csr_w[e + 1];
        float4 a = *(const float4*)&Tc[(size_t)s0 * 128 + f4];
        float4 b = *(const float4*)&Tc[(size_t)s1 * 128 + f4];
        acc.x += w0 * a.x + w1 * b.x; acc.y += w0 * a.y + w1 * b.y;
        acc.z += w0 * a.z + w1 * b.z; acc.w += w0 * a.w + w1 * b.w;
    }
    if (e < e1) {
        float w0 = csr_w[e];
        float4 a = *(const float4*)&Tc[(size_t)csr_s[e] * 128 + f4];
        acc.x += w0 * a.x; acc.y += w0 * a.y; acc.z += w0 * a.z; acc.w += w0 * a.w;
    }
    float4 p = *(const float4*)&G3[(size_t)n * 384 + f4];
    float4 r = *(const float4*)&G3[(size_t)n * 384 + 256 + f4];
    float4 v;
    v.x = p.x - r.x + acc.x; v.y = p.y - r.y + acc.y;
    v.z = p.z - r.z + acc.z; v.w = p.w - r.w + acc.w;
    *(float4*)&Fbuf[(size_t)n * 128 + f4] = v;
    red_s[g][f4 + 0] = v.x; red_s[g][f4 + 1] = v.y;
    red_s[g][f4 + 2] = v.z; red_s[g][f4 + 3] = v.w;
    red_q[g][f4 + 0] = v.x * v.x; red_q[g][f4 + 1] = v.y * v.y;
    red_q[g][f4 + 2] = v.z * v.z; red_q[g][f4 + 3] = v.w * v.w;
    __syncthreads();
    const int t = threadIdx.x;
    if (t < 128) {
        float s = 0.f, q = 0.f;
        #pragma unroll
        for (int gg = 0; gg < 8; ++gg) { s += red_s[gg][t]; q += red_q[gg][t]; }
        atomicAdd(&sums[t], s);
        atomicAdd(&sums[128 + t], q);
    }
}

// ---------------- fused BN3 (inline coeffs) + FC(128->6) + log_softmax ----------------

__global__ __launch_bounds__(256) void final_kernel(const float* __restrict__ h,
                                                    const float* __restrict__ sums,
                                                    const float* __restrict__ g3,
                                                    const float* __restrict__ be3,
                                                    const float* __restrict__ fcW,
                                                    const float* __restrict__ fcb,
                                                    float* __restrict__ out) {
    const int t = threadIdx.x, lane = t & 63, wid = t >> 6;
    const int r = blockIdx.x * 4 + wid;
    if (r >= N_NODES) return;
    const float invM = 1.0f / (float)N_NODES;
    float v[6] = {0.f, 0.f, 0.f, 0.f, 0.f, 0.f};
    #pragma unroll
    for (int kk = 0; kk < 2; ++kk) {
        int k = lane + kk * 64;
        float mu = sums[k] * invM;
        float sc = g3[k] * rsqrtf(sums[128 + k] * invM - mu * mu + 1e-5f);
        float sh = be3[k] - mu * sc;
        float x = h[(size_t)r * 128 + k] * sc + sh;
        #pragma unroll
        for (int j = 0; j < 6; ++j) v[j] += x * fcW[k * 6 + j];
    }
    #pragma unroll
    for (int j = 0; j < 6; ++j)
        #pragma unroll
        for (int off = 32; off > 0; off >>= 1) v[j] += __shfl_down(v[j], off);
    if (lane == 0) {
        #pragma unroll
        for (int j = 0; j < 6; ++j) v[j] += fcb[j];
        float m = v[0];
        #pragma unroll
        for (int j = 1; j < 6; ++j) m = fmaxf(m, v[j]);
        float s = 0.f;
        #pragma unroll
        for (int j = 0; j < 6; ++j) s += expf(v[j] - m);
        float l = m + logf(s);
        #pragma unroll
        for (int j = 0; j < 6; ++j) out[r * 6 + j] = v[j] - l;
    }
}

// ---------------- launch ----------------

extern "C" void kernel_launch(void* const* d_in, const int* in_sizes, int n_in,
                              void* d_out, int out_size, void* d_ws, size_t ws_size,
                              hipStream_t stream) {
    (void)in_sizes; (void)n_in; (void)out_size; (void)ws_size;
    const float* x   = (const float*)d_in[0];
    const int*   ei  = (const int*)d_in[1];
    const float* ea  = (const float*)d_in[2];
    const float* W1  = (const float*)d_in[3];
    // b1/b2/b3 (d_in[4],[9],[15]) cancel under training-mode BN
    const float* g1  = (const float*)d_in[5];
    const float* be1 = (const float*)d_in[6];
    const float* W2a = (const float*)d_in[7];
    const float* W2b = (const float*)d_in[8];
    const float* g2  = (const float*)d_in[10];
    const float* be2 = (const float*)d_in[11];
    const float* W3a = (const float*)d_in[12];
    const float* W3b = (const float*)d_in[13];
    const float* W3c = (const float*)d_in[14];
    const float* g3  = (const float*)d_in[16];
    const float* be3 = (const float*)d_in[17];
    const float* fcW = (const float*)d_in[18];
    const float* fcb = (const float*)d_in[19];
    float* out = (float*)d_out;

    const int* src = ei;
    const int* dst = ei + N_EDGES;

    char* w = (char*)d_ws;
    size_t off = 0;
    auto alloc = [&](size_t bytes) -> void* {
        void* p = w + off;
        off += (bytes + 4095) & ~(size_t)4095;
        return p;
    };
    // zeroed region first
    float* deg    = (float*)alloc(N_NODES * 4);
    int*   cnt    = (int*)  alloc(N_NODES * 4);
    int*   fillc  = (int*)  alloc(N_NODES * 4);
    float* sums1  = (float*)alloc(1024 * 4);
    float* sums2  = (float*)alloc(1024 * 4);
    float* sums3  = (float*)alloc(1024 * 4);
    size_t zero_bytes = off;
    float* dis    = (float*)alloc(N_NODES * 4);
    int*   rowptr = (int*)  alloc((N_NODES + 1) * 4);
    int*   csr_s  = (int*)  alloc(N_EDGES * 4);
    float* csr_w  = (float*)alloc(N_EDGES * 4);
    us* B1T = (us*)alloc((size_t)512 * 1536 * 2);
    us* B2T = (us*)alloc((size_t)512 * 1024 * 2);
    us* B3T = (us*)alloc((size_t)384 * 512 * 2);
    // aliased big slots
    us* slotA = (us*)alloc((size_t)MPAD * 1536 * 2);          // A'1/A'2/A'3 (packed)
    float* slotG = (float*)alloc((size_t)N_NODES * 512 * 4);  // G1/G2/G3
    float* slotC = (float*)alloc((size_t)N_NODES * 256 * 4);  // out2 ; then Tc
    float* bufF  = (float*)alloc((size_t)N_NODES * 128 * 4);

    us* A1 = slotA;
    us* A2 = slotA;
    us* A3 = slotA;
    float* G1 = slotG;
    float* G2 = slotG;
    float* G3 = slotG;
    float* out2 = slotC;
    float* bufTc = slotC;    // overwrites out2 after it is consumed

    hipMemsetAsync(d_ws, 0, zero_bytes, stream);

    // graph preprocessing -> dst-CSR with normalized weights
    deg_kernel<<<N_EDGES / 256, 256, 0, stream>>>(src, dst, ea, deg, cnt);
    dis_scan_kernel<<<40, 1024, 0, stream>>>(deg, cnt, dis, rowptr);
    fill_kernel<<<N_EDGES / 256, 256, 0, stream>>>(src, dst, ea, dis, rowptr, fillc,
                                                   csr_s, csr_w);

    // all fp32->bf16 hi/lo packed conversions in one dispatch
    cvt_all_kernel<<<2128, 256, 0, stream>>>(x, A1, W1, B1T, W2a, W2b, B2T,
                                             W3a, W3b, W3c, B3T);

    // ---- layer 1: G1 = x @ W1 (bf16x3) + fused BN stats; BN+ReLU+cvt -> A'2 ----
    mfma_gemm_kernel<<<632, 256, 0, stream>>>(A1, B1T, G1, N_NODES, 768, 512, 8, sums1);
    bn_relu_cvt_kernel<<<dim3(40, 32), 256, 0, stream>>>(G1, sums1, g1, be1, A2, 512);

    // ---- layer 2: G2 = h1 @ [W2a|W2b]; out2 = y0 + P y1; stats; cvt -> A'3 ----
    mfma_gemm_kernel<<<632, 256, 0, stream>>>(A2, B2T, G2, N_NODES, 512, 512, 8, nullptr);
    prop_l2_kernel<<<2500, 256, 0, stream>>>(G2, rowptr, csr_s, csr_w, out2);
    bn_stats256_kernel<<<500, 256, 0, stream>>>(out2, sums2);
    bn_relu_cvt_kernel<<<dim3(40, 16), 256, 0, stream>>>(out2, sums2, g2, be2, A3, 256);

    // ---- layer 3: G3 = h2 @ [W3a|W3b|W3c] = [f0|g1|g2] ----
    mfma_gemm_kernel<<<474, 256, 0, stream>>>(A3, B3T, G3, N_NODES, 256, 384, 6, nullptr);
    // Tc = g1 + 2 P g2 ; out3 = f0 - g2 + P Tc  (+ fused BN stats)
    prop3a_kernel<<<1250, 256, 0, stream>>>(G3, rowptr, csr_s, csr_w, bufTc);
    prop3b_combine_kernel<<<1250, 256, 0, stream>>>(G3, bufTc, rowptr, csr_s, csr_w,
                                                    bufF, sums3);

    // ---- BN3 (inline coeffs) + FC + log_softmax fused ----
    final_kernel<<<2500, 256, 0, stream>>>(bufF, sums3, g3, be3, fcW, fcb, out);
}

// Round 12
// 344.746 us; speedup vs baseline: 1.4124x; 1.0105x over previous
//
#include <hip/hip_runtime.h>
#include <hip/hip_bf16.h>
#include <cstdint>

#define N_NODES 10000
#define N_EDGES 160000
#define MPAD    10112   // 79 * 128

typedef __attribute__((ext_vector_type(8))) short short8;
typedef __attribute__((ext_vector_type(4))) float floatx4;
typedef unsigned short us;

// ---------------- helpers ----------------

__device__ __forceinline__ us bf16_rn(float f) {
    union { float f; unsigned u; } c{f};
    unsigned r = c.u + 0x7FFF + ((c.u >> 16) & 1);   // round-to-nearest-even
    return (us)(r >> 16);
}
__device__ __forceinline__ float bf16_to_f(us h) {
    union { unsigned u; float f; } c{(unsigned)h << 16};
    return c.f;
}
__device__ __forceinline__ unsigned pack_hi2(float a, float b) {
    return (unsigned)bf16_rn(a) | ((unsigned)bf16_rn(b) << 16);
}
__device__ __forceinline__ unsigned pack_lo2(float a, float b) {
    float ra = a - bf16_to_f(bf16_rn(a));
    float rb = b - bf16_to_f(bf16_rn(b));
    return (unsigned)bf16_rn(ra) | ((unsigned)bf16_rn(rb) << 16);
}

__device__ __forceinline__ void gload_lds16(const void* g, void* l) {
    __builtin_amdgcn_global_load_lds(
        (const __attribute__((address_space(1))) unsigned int*)g,
        (__attribute__((address_space(3))) unsigned int*)l, 16, 0, 0);
}

// ================= tile-packed bf16 layouts (verified round 5) =================
// A_packed: per 128-row panel pa, per 32-k tile kt: 4096 elems as
//   elem((kq*128 + rr)*8 + e); width axis = [hi | lo] concat (2K).
// B_packed: per 64-col panel pb, per 32-k tile: 2048 elems, (kq*64 + c)*8 + e.

// ---------------- edge preprocessing ----------------

__global__ void deg_kernel(const int* __restrict__ src, const int* __restrict__ dst,
                           const float* __restrict__ ew,
                           float* __restrict__ deg, int* __restrict__ cnt) {
    int e = blockIdx.x * blockDim.x + threadIdx.x;
    if (e >= N_EDGES) return;
    atomicAdd(&deg[src[e]], ew[e]);
    atomicAdd(&cnt[dst[e]], 1);
}

// block 0: exclusive scan cnt -> rowptr ; blocks 1..39: dis = rsqrt(deg)
__global__ __launch_bounds__(1024) void dis_scan_kernel(const float* __restrict__ deg,
                                                        const int* __restrict__ cnt,
                                                        float* __restrict__ dis,
                                                        int* __restrict__ rowptr) {
    const int t = threadIdx.x;
    if (blockIdx.x != 0) {
        int n = (blockIdx.x - 1) * 1024 + t;
        if (n < N_NODES) {
            float d = deg[n];
            dis[n] = d > 0.f ? rsqrtf(d) : 0.f;
        }
        return;
    }
    __shared__ int wsum[16];
    const int lane = t & 63, wid = t >> 6;
    int carry = 0;
    for (int base = 0; base < N_NODES; base += 1024) {
        int i = base + t;
        int v = (i < N_NODES) ? cnt[i] : 0;
        int s = v;
        #pragma unroll
        for (int off = 1; off < 64; off <<= 1) {
            int u = __shfl_up(s, off);
            if (lane >= off) s += u;
        }
        if (lane == 63) wsum[wid] = s;
        __syncthreads();
        int woff = 0, tot = 0;
        for (int ww = 0; ww < 16; ++ww) {
            int xv = wsum[ww];
            if (ww < wid) woff += xv;
            tot += xv;
        }
        if (i < N_NODES) rowptr[i + 1] = carry + woff + s;
        carry += tot;
        __syncthreads();
    }
    if (t == 0) rowptr[0] = 0;
}

__global__ void fill_kernel(const int* __restrict__ src, const int* __restrict__ dst,
                            const float* __restrict__ ew, const float* __restrict__ dis,
                            const int* __restrict__ rowptr, int* __restrict__ fill,
                            int* __restrict__ csr_src, float* __restrict__ csr_w) {
    int e = blockIdx.x * blockDim.x + threadIdx.x;
    if (e >= N_EDGES) return;
    int s = src[e], d = dst[e];
    int pos = rowptr[d] + atomicAdd(&fill[d], 1);
    csr_src[pos] = s;
    csr_w[pos] = -dis[s] * ew[e] * dis[d];
}

// ---------------- packed conversions ----------------

__device__ __forceinline__ void cvt_x_body(int bx, int k16, const float* __restrict__ x,
                                           us* __restrict__ Ap) {
    int m = bx * 256 + threadIdx.x;
    if (m >= N_NODES) return;
    const float4* p = (const float4*)(x + (size_t)m * 768 + k16 * 16);
    float4 v0 = p[0], v1 = p[1], v2 = p[2], v3 = p[3];
    uint4 hi0, hi1, lo0, lo1;
    hi0.x = pack_hi2(v0.x, v0.y); hi0.y = pack_hi2(v0.z, v0.w);
    hi0.z = pack_hi2(v1.x, v1.y); hi0.w = pack_hi2(v1.z, v1.w);
    hi1.x = pack_hi2(v2.x, v2.y); hi1.y = pack_hi2(v2.z, v2.w);
    hi1.z = pack_hi2(v3.x, v3.y); hi1.w = pack_hi2(v3.z, v3.w);
    lo0.x = pack_lo2(v0.x, v0.y); lo0.y = pack_lo2(v0.z, v0.w);
    lo0.z = pack_lo2(v1.x, v1.y); lo0.w = pack_lo2(v1.z, v1.w);
    lo1.x = pack_lo2(v2.x, v2.y); lo1.y = pack_lo2(v2.z, v2.w);
    lo1.z = pack_lo2(v3.x, v3.y); lo1.w = pack_lo2(v3.z, v3.w);
    int pa = m >> 7, rr = m & 127;
    int kt = k16 >> 1, kqb = (k16 & 1) * 2;
    size_t th = ((size_t)pa * 48 + kt) * 4096;
    size_t tl = ((size_t)pa * 48 + 24 + kt) * 4096;
    *(uint4*)&Ap[th + ((kqb + 0) * 128 + rr) * 8] = hi0;
    *(uint4*)&Ap[th + ((kqb + 1) * 128 + rr) * 8] = hi1;
    *(uint4*)&Ap[tl + ((kqb + 0) * 128 + rr) * 8] = lo0;
    *(uint4*)&Ap[tl + ((kqb + 1) * 128 + rr) * 8] = lo1;
}

__device__ __forceinline__ void cvt_w_body(int bx, int k16, const float* __restrict__ W,
                                           us* __restrict__ Bp, int K, int N) {
    int n = bx * 256 + threadIdx.x;
    if (n >= N) return;
    float v[16];
    #pragma unroll
    for (int j = 0; j < 16; ++j) v[j] = W[(size_t)(k16 * 16 + j) * N + n];
    uint4 hi0, hi1, lo0, lo1;
    hi0.x = pack_hi2(v[0], v[1]);  hi0.y = pack_hi2(v[2], v[3]);
    hi0.z = pack_hi2(v[4], v[5]);  hi0.w = pack_hi2(v[6], v[7]);
    hi1.x = pack_hi2(v[8], v[9]);  hi1.y = pack_hi2(v[10], v[11]);
    hi1.z = pack_hi2(v[12], v[13]); hi1.w = pack_hi2(v[14], v[15]);
    lo0.x = pack_lo2(v[0], v[1]);  lo0.y = pack_lo2(v[2], v[3]);
    lo0.z = pack_lo2(v[4], v[5]);  lo0.w = pack_lo2(v[6], v[7]);
    lo1.x = pack_lo2(v[8], v[9]);  lo1.y = pack_lo2(v[10], v[11]);
    lo1.z = pack_lo2(v[12], v[13]); lo1.w = pack_lo2(v[14], v[15]);
    int pb = n >> 6, c = n & 63;
    int NKTB = K >> 4;
    int kt = k16 >> 1, kqb = (k16 & 1) * 2;
    size_t th = ((size_t)pb * NKTB + kt) * 2048;
    size_t tl = ((size_t)pb * NKTB + (K >> 5) + kt) * 2048;
    *(uint4*)&Bp[th + ((kqb + 0) * 64 + c) * 8] = hi0;
    *(uint4*)&Bp[th + ((kqb + 1) * 64 + c) * 8] = hi1;
    *(uint4*)&Bp[tl + ((kqb + 0) * 64 + c) * 8] = lo0;
    *(uint4*)&Bp[tl + ((kqb + 1) * 64 + c) * 8] = lo1;
}

__global__ __launch_bounds__(256) void cvt_all_kernel(const float* __restrict__ x,
                                                      us* __restrict__ A1,
                                                      const float* __restrict__ W1,
                                                      us* __restrict__ B1T,
                                                      const float* __restrict__ W2a,
                                                      const float* __restrict__ W2b,
                                                      us* __restrict__ B2T,
                                                      const float* __restrict__ W3a,
                                                      const float* __restrict__ W3b,
                                                      const float* __restrict__ W3c,
                                                      us* __restrict__ B3T) {
    int b = blockIdx.x;
    if (b < 1920) { cvt_x_body(b % 40, b / 40, x, A1); return; }
    b -= 1920;
    if (b < 96)  { cvt_w_body(b & 1, b >> 1, W1, B1T, 768, 512); return; }
    b -= 96;
    if (b < 32)  { cvt_w_body(0, b, W2a, B2T, 512, 256); return; }
    b -= 32;
    if (b < 32)  { cvt_w_body(0, b, W2b, B2T + (size_t)4 * 32 * 2048, 512, 256); return; }
    b -= 32;
    if (b < 16)  { cvt_w_body(0, b, W3a, B3T, 256, 128); return; }
    b -= 16;
    if (b < 16)  { cvt_w_body(0, b, W3b, B3T + (size_t)2 * 16 * 2048, 256, 128); return; }
    b -= 16;
    cvt_w_body(0, b, W3c, B3T + (size_t)4 * 16 * 2048, 256, 128);
}

// fused BN(inline coeffs)+ReLU+cvt -> packed A. grid (40, F/16)
__global__ __launch_bounds__(256) void bn_relu_cvt_kernel(const float* __restrict__ G,
                                                          const float* __restrict__ sums,
                                                          const float* __restrict__ g,
                                                          const float* __restrict__ be,
                                                          us* __restrict__ Ap, int F) {
    const int k16 = blockIdx.y;
    int m = blockIdx.x * 256 + threadIdx.x;
    if (m >= N_NODES) return;
    const float invM = 1.0f / (float)N_NODES;
    float sc[16], sh[16];
    #pragma unroll
    for (int j = 0; j < 16; ++j) {
        int c = k16 * 16 + j;
        float mu = sums[c] * invM;
        float s = g[c] * rsqrtf(sums[F + c] * invM - mu * mu + 1e-5f);
        sc[j] = s;
        sh[j] = be[c] - mu * s;
    }
    const float4* p = (const float4*)(G + (size_t)m * F + k16 * 16);
    float v[16];
    #pragma unroll
    for (int q = 0; q < 4; ++q) {
        float4 t4 = p[q];
        v[q * 4 + 0] = t4.x; v[q * 4 + 1] = t4.y;
        v[q * 4 + 2] = t4.z; v[q * 4 + 3] = t4.w;
    }
    #pragma unroll
    for (int j = 0; j < 16; ++j) v[j] = fmaxf(v[j] * sc[j] + sh[j], 0.f);
    uint4 hi0, hi1, lo0, lo1;
    hi0.x = pack_hi2(v[0], v[1]);  hi0.y = pack_hi2(v[2], v[3]);
    hi0.z = pack_hi2(v[4], v[5]);  hi0.w = pack_hi2(v[6], v[7]);
    hi1.x = pack_hi2(v[8], v[9]);  hi1.y = pack_hi2(v[10], v[11]);
    hi1.z = pack_hi2(v[12], v[13]); hi1.w = pack_hi2(v[14], v[15]);
    lo0.x = pack_lo2(v[0], v[1]);  lo0.y = pack_lo2(v[2], v[3]);
    lo0.z = pack_lo2(v[4], v[5]);  lo0.w = pack_lo2(v[6], v[7]);
    lo1.x = pack_lo2(v[8], v[9]);  lo1.y = pack_lo2(v[10], v[11]);
    lo1.z = pack_lo2(v[12], v[13]); lo1.w = pack_lo2(v[14], v[15]);
    int pa = m >> 7, rr = m & 127;
    int NKT = F >> 4;
    int kt = k16 >> 1, kqb = (k16 & 1) * 2;
    size_t th = ((size_t)pa * NKT + kt) * 4096;
    size_t tl = ((size_t)pa * NKT + (F >> 5) + kt) * 4096;
    *(uint4*)&Ap[th + ((kqb + 0) * 128 + rr) * 8] = hi0;
    *(uint4*)&Ap[th + ((kqb + 1) * 128 + rr) * 8] = hi1;
    *(uint4*)&Ap[tl + ((kqb + 0) * 128 + rr) * 8] = lo0;
    *(uint4*)&Ap[tl + ((kqb + 1) * 128 + rr) * 8] = lo1;
}

// ---------------- bf16x3 MFMA GEMM: 128x64 tile, BK=64, double-buffered (r9 verified) ----------------

__global__ __launch_bounds__(256, 3) void mfma_gemm_kernel(
        const us* __restrict__ Ap,
        const us* __restrict__ BpT,
        float* __restrict__ C,
        int M, int Ksub, int Nc, int ncb,
        float* __restrict__ sums) {
    __shared__ us As[2][8192];   // 2 bufs x two 32-k tiles (128 rows)
    __shared__ us Bs[2][4096];   // 2 bufs x two 32-k tiles (64 cols)
    const int t = threadIdx.x;
    const int w = t >> 6, l = t & 63;

    int nwg = gridDim.x, bid = blockIdx.x;
    int q = nwg >> 3, r = nwg & 7;
    int xcd = bid & 7, idx = bid >> 3;
    int wgid = (xcd < r ? xcd * (q + 1) : r * (q + 1) + (xcd - r) * q) + idx;
    const int row0 = (wgid / ncb) * 128;
    const int col0 = (wgid % ncb) * 64;

    const int NKTA = Ksub >> 4;
    const int nt = (3 * Ksub) >> 5;     // 32-k tiles (even for all layers)
    const int wr = w >> 1, wc = w & 1;
    const int lr = l & 15, kq = l >> 4;

    const us* Abase = Ap + (size_t)(row0 >> 7) * NKTA * 4096;
    const us* Bbase = BpT + (size_t)(col0 >> 6) * NKTA * 2048;

    // stage one 32-k tile (kt) into buffer `buf`, half-slot kt&1
    auto stage = [&](int buf, int kt) {
        int k0 = kt << 5;
        int kA = (k0 < 2 * Ksub) ? k0 : k0 - 2 * Ksub;   // A blocks: hi, lo, hi
        int kB = (k0 < Ksub)     ? k0 : k0 - Ksub;       // B blocks: hi, hi, lo
        const us* At = Abase + (size_t)(kA >> 5) * 4096;
        const us* Bt = Bbase + (size_t)(kB >> 5) * 2048;
        char* adst = (char*)As[buf] + (kt & 1) * 8192;
        char* bdst = (char*)Bs[buf] + (kt & 1) * 4096;
        gload_lds16(At + (w * 64 + l) * 8,       adst + w * 1024);
        gload_lds16(At + ((w + 4) * 64 + l) * 8, adst + (w + 4) * 1024);
        gload_lds16(Bt + (w * 64 + l) * 8,       bdst + w * 1024);
    };

    floatx4 acc[4][2] = {};

    stage(0, 0); stage(0, 1);
    __syncthreads();                      // vmcnt(0) drain: buf0 ready
    int cur = 0;
    for (int kt2 = 0; kt2 < (nt >> 1); ++kt2) {
        if (kt2 + 1 < (nt >> 1)) {        // prefetch next 64-k step
            stage(cur ^ 1, kt2 * 2 + 2);
            stage(cur ^ 1, kt2 * 2 + 3);
        }
        #pragma unroll
        for (int sub = 0; sub < 2; ++sub) {
            const us* Ac = &As[cur][sub * 4096];
            const us* Bc = &Bs[cur][sub * 2048];
            short8 af[4], bfr[2];
            #pragma unroll
            for (int m = 0; m < 4; ++m)
                af[m] = *(const short8*)&Ac[(kq * 128 + wr * 64 + m * 16 + lr) * 8];
            #pragma unroll
            for (int n = 0; n < 2; ++n)
                bfr[n] = *(const short8*)&Bc[(kq * 64 + wc * 32 + n * 16 + lr) * 8];
            #pragma unroll
            for (int m = 0; m < 4; ++m)
                #pragma unroll
                for (int n = 0; n < 2; ++n)
                    acc[m][n] = __builtin_amdgcn_mfma_f32_16x16x32_bf16(
                        af[m], bfr[n], acc[m][n], 0, 0, 0);
        }
        __syncthreads();                  // next buf ready; cur reads done
        cur ^= 1;
    }

    // C/D layout: col=lane&15, row=(lane>>4)*4+j  [m89/m91]
    #pragma unroll
    for (int m = 0; m < 4; ++m) {
        int rb = row0 + wr * 64 + m * 16 + kq * 4;
        #pragma unroll
        for (int j = 0; j < 4; ++j) {
            int rr = rb + j;
            if (rr < M) {
                #pragma unroll
                for (int n = 0; n < 2; ++n)
                    C[(size_t)rr * Nc + col0 + wc * 32 + n * 16 + lr] = acc[m][n][j];
            }
        }
    }

    if (sums) {
        float s[2] = {0.f, 0.f}, qv[2] = {0.f, 0.f};
        #pragma unroll
        for (int m = 0; m < 4; ++m)
            #pragma unroll
            for (int n = 0; n < 2; ++n)
                #pragma unroll
                for (int j = 0; j < 4; ++j) {
                    float v = acc[m][n][j];
                    s[n] += v; qv[n] += v * v;
                }
        float* red = (float*)As;
        int g8 = wr * 4 + kq;
        #pragma unroll
        for (int n = 0; n < 2; ++n) {
            int c = wc * 32 + n * 16 + lr;
            red[g8 * 128 + c * 2 + 0] = s[n];
            red[g8 * 128 + c * 2 + 1] = qv[n];
        }
        __syncthreads();
        if (t < 128) {
            float tot = 0.f;
            #pragma unroll
            for (int g = 0; g < 8; ++g) tot += red[g * 128 + t];
            int c = t >> 1, e = t & 1;
            atomicAdd(&sums[e * 512 + col0 + c], tot);
        }
    }
}

// ---------------- graph propagation v3: shfl-distributed indices, 4-deep gathers ----------------
// Chunk-load edge indices+weights with ONE coalesced vector load per group,
// distribute via __shfl (no memory dep), gather 4 rows concurrently.

__global__ __launch_bounds__(256) void prop_l2_kernel(const float* __restrict__ G2,
                                                      const int* __restrict__ rowptr,
                                                      const int* __restrict__ csr_s,
                                                      const float* __restrict__ csr_w,
                                                      float* __restrict__ out2) {
    const int g = threadIdx.x >> 6, lane = threadIdx.x & 63;
    const int n = blockIdx.x * 4 + g;
    const int f4 = lane * 4;
    const int e0 = rowptr[n], e1 = rowptr[n + 1];
    float4 a0 = {0,0,0,0}, a1 = {0,0,0,0}, a2 = {0,0,0,0}, a3 = {0,0,0,0};
    for (int base = e0; base < e1; base += 64) {
        int m = min(64, e1 - base);
        int idx = 0; float wv = 0.f;
        if (base + lane < e1) { idx = csr_s[base + lane]; wv = csr_w[base + lane]; }
        int j = 0;
        for (; j + 3 < m; j += 4) {
            int s0 = __shfl(idx, j);     float w0 = __shfl(wv, j);
            int s1 = __shfl(idx, j + 1); float w1 = __shfl(wv, j + 1);
            int s2 = __shfl(idx, j + 2); float w2 = __shfl(wv, j + 2);
            int s3 = __shfl(idx, j + 3); float w3 = __shfl(wv, j + 3);
            float4 v0 = *(const float4*)&G2[(size_t)s0 * 512 + 256 + f4];
            float4 v1 = *(const float4*)&G2[(size_t)s1 * 512 + 256 + f4];
            float4 v2 = *(const float4*)&G2[(size_t)s2 * 512 + 256 + f4];
            float4 v3 = *(const float4*)&G2[(size_t)s3 * 512 + 256 + f4];
            a0.x += w0 * v0.x; a0.y += w0 * v0.y; a0.z += w0 * v0.z; a0.w += w0 * v0.w;
            a1.x += w1 * v1.x; a1.y += w1 * v1.y; a1.z += w1 * v1.z; a1.w += w1 * v1.w;
            a2.x += w2 * v2.x; a2.y += w2 * v2.y; a2.z += w2 * v2.z; a2.w += w2 * v2.w;
            a3.x += w3 * v3.x; a3.y += w3 * v3.y; a3.z += w3 * v3.z; a3.w += w3 * v3.w;
        }
        for (; j < m; ++j) {
            int s0 = __shfl(idx, j); float w0 = __shfl(wv, j);
            float4 v0 = *(const float4*)&G2[(size_t)s0 * 512 + 256 + f4];
            a0.x += w0 * v0.x; a0.y += w0 * v0.y; a0.z += w0 * v0.z; a0.w += w0 * v0.w;
        }
    }
    float4 base4 = *(const float4*)&G2[(size_t)n * 512 + f4];
    float4 v;
    v.x = base4.x + (a0.x + a1.x) + (a2.x + a3.x);
    v.y = base4.y + (a0.y + a1.y) + (a2.y + a3.y);
    v.z = base4.z + (a0.z + a1.z) + (a2.z + a3.z);
    v.w = base4.w + (a0.w + a1.w) + (a2.w + a3.w);
    *(float4*)&out2[(size_t)n * 256 + f4] = v;
}

__global__ __launch_bounds__(256) void bn_stats256_kernel(const float* __restrict__ h,
                                                          float* __restrict__ sums) {
    const int t = threadIdx.x;
    int r0 = blockIdx.x * 20, r1 = min(r0 + 20, N_NODES);
    float s = 0.f, q = 0.f;
    for (int r = r0; r < r1; ++r) {
        float v = h[(size_t)r * 256 + t];
        s += v; q += v * v;
    }
    atomicAdd(&sums[t], s);
    atomicAdd(&sums[256 + t], q);
}

// Tc[n] = G3[n][128..256) + 2 * sum_e w * G3[src][256+f]
__global__ __launch_bounds__(256) void prop3a_kernel(const float* __restrict__ G3,
                                                     const int* __restrict__ rowptr,
                                                     const int* __restrict__ csr_s,
                                                     const float* __restrict__ csr_w,
                                                     float* __restrict__ Tc) {
    const int g = threadIdx.x >> 5, lane = threadIdx.x & 31;
    const int n = blockIdx.x * 8 + g;
    const int f4 = lane * 4;
    const int e0 = rowptr[n], e1 = rowptr[n + 1];
    float4 a0 = {0,0,0,0}, a1 = {0,0,0,0}, a2 = {0,0,0,0}, a3 = {0,0,0,0};
    for (int base = e0; base < e1; base += 32) {
        int m = min(32, e1 - base);
        int idx = 0; float wv = 0.f;
        if (base + lane < e1) { idx = csr_s[base + lane]; wv = csr_w[base + lane]; }
        int j = 0;
        for (; j + 3 < m; j += 4) {
            int s0 = __shfl(idx, j, 32);     float w0 = __shfl(wv, j, 32);
            int s1 = __shfl(idx, j + 1, 32); float w1 = __shfl(wv, j + 1, 32);
            int s2 = __shfl(idx, j + 2, 32); float w2 = __shfl(wv, j + 2, 32);
            int s3 = __shfl(idx, j + 3, 32); float w3 = __shfl(wv, j + 3, 32);
            float4 v0 = *(const float4*)&G3[(size_t)s0 * 384 + 256 + f4];
            float4 v1 = *(const float4*)&G3[(size_t)s1 * 384 + 256 + f4];
            float4 v2 = *(const float4*)&G3[(size_t)s2 * 384 + 256 + f4];
            float4 v3 = *(const float4*)&G3[(size_t)s3 * 384 + 256 + f4];
            a0.x += w0 * v0.x; a0.y += w0 * v0.y; a0.z += w0 * v0.z; a0.w += w0 * v0.w;
            a1.x += w1 * v1.x; a1.y += w1 * v1.y; a1.z += w1 * v1.z; a1.w += w1 * v1.w;
            a2.x += w2 * v2.x; a2.y += w2 * v2.y; a2.z += w2 * v2.z; a2.w += w2 * v2.w;
            a3.x += w3 * v3.x; a3.y += w3 * v3.y; a3.z += w3 * v3.z; a3.w += w3 * v3.w;
        }
        for (; j < m; ++j) {
            int s0 = __shfl(idx, j, 32); float w0 = __shfl(wv, j, 32);
            float4 v0 = *(const float4*)&G3[(size_t)s0 * 384 + 256 + f4];
            a0.x += w0 * v0.x; a0.y += w0 * v0.y; a0.z += w0 * v0.z; a0.w += w0 * v0.w;
        }
    }
    float4 g1r = *(const float4*)&G3[(size_t)n * 384 + 128 + f4];  // own row, coalesced
    float4 v;
    v.x = g1r.x + 2.f * ((a0.x + a1.x) + (a2.x + a3.x));
    v.y = g1r.y + 2.f * ((a0.y + a1.y) + (a2.y + a3.y));
    v.z = g1r.z + 2.f * ((a0.z + a1.z) + (a2.z + a3.z));
    v.w = g1r.w + 2.f * ((a0.w + a1.w) + (a2.w + a3.w));
    *(float4*)&Tc[(size_t)n * 128 + f4] = v;
}

// out3 = f0 - g2 + P Tc ; fused BN stats. Single-row gather per edge.
__global__ __launch_bounds__(256) void prop3b_combine_kernel(const float* __restrict__ G3,
                                                             const float* __restrict__ Tc,
                                                             const int* __restrict__ rowptr,
                                                             const int* __restrict__ csr_s,
                                                             const float* __restrict__ csr_w,
                                                             float* __restrict__ Fbuf,
                                                             float* __restrict__ sums) {
    __shared__ float red_s[8][128];
    __shared__ float red_q[8][128];
    const int g = threadIdx.x >> 5, lane = threadIdx.x & 31;
    const int n = blockIdx.x * 8 + g;
    const int f4 = lane * 4;
    const int e0 = rowptr[n], e1 = rowptr[n + 1];
    float4 a0 = {0,0,0,0}, a1 = {0,0,0,0}, a2 = {0,0,0,0}, a3 = {0,0,0,0};
    for (int base = e0; base < e1; base += 32) {
        int m = min(32, e1 - base);
        int idx = 0; float wv = 0.f;
        if (base + lane < e1) { idx = csr_s[base + lane]; wv = csr_w[base + lane]; }
        int j = 0;
        for (; j + 3 < m; j += 4) {
            int s0 = __shfl(idx, j, 32);     float w0 = __shfl(wv, j, 32);
            int s1 = __shfl(idx, j + 1, 32); float w1 = __shfl(wv, j + 1, 32);
            int s2 = __shfl(idx, j + 2, 32); float w2 = __shfl(wv, j + 2, 32);
            int s3 = __shfl(idx, j + 3, 32); float w3 = __shfl(wv, j + 3, 32);
            float4 v0 = *(const float4*)&Tc[(size_t)s0 * 128 + f4];
            float4 v1 = *(const float4*)&Tc[(size_t)s1 * 128 + f4];
            float4 v2 = *(const float4*)&Tc[(size_t)s2 * 128 + f4];
            float4 v3 = *(const float4*)&Tc[(size_t)s3 * 128 + f4];
            a0.x += w0 * v0.x; a0.y += w0 * v0.y; a0.z += w0 * v0.z; a0.w += w0 * v0.w;
            a1.x += w1 * v1.x; a1.y += w1 * v1.y; a1.z += w1 * v1.z; a1.w += w1 * v1.w;
            a2.x += w2 * v2.x; a2.y += w2 * v2.y; a2.z += w2 * v2.z; a2.w += w2 * v2.w;
            a3.x += w3 * v3.x; a3.y += w3 * v3.y; a3.z += w3 * v3.z; a3.w += w3 * v3.w;
        }
        for (; j < m; ++j) {
            int s0 = __shfl(idx, j, 32); float w0 = __shfl(wv, j, 32);
            float4 v0 = *(const float4*)&Tc[(size_t)s0 * 128 + f4];
            a0.x += w0 * v0.x; a0.y += w0 * v0.y; a0.z += w0 * v0.z; a0.w += w0 * v0.w;
        }
    }
    float4 p = *(const float4*)&G3[(size_t)n * 384 + f4];
    float4 r = *(const float4*)&G3[(size_t)n * 384 + 256 + f4];
    float4 v;
    v.x = p.x - r.x + (a0.x + a1.x) + (a2.x + a3.x);
    v.y = p.y - r.y + (a0.y + a1.y) + (a2.y + a3.y);
    v.z = p.z - r.z + (a0.z + a1.z) + (a2.z + a3.z);
    v.w = p.w - r.w + (a0.w + a1.w) + (a2.w + a3.w);
    *(float4*)&Fbuf[(size_t)n * 128 + f4] = v;
    red_s[g][f4 + 0] = v.x; red_s[g][f4 + 1] = v.y;
    red_s[g][f4 + 2] = v.z; red_s[g][f4 + 3] = v.w;
    red_q[g][f4 + 0] = v.x * v.x; red_q[g][f4 + 1] = v.y * v.y;
    red_q[g][f4 + 2] = v.z * v.z; red_q[g][f4 + 3] = v.w * v.w;
    __syncthreads();
    const int t = threadIdx.x;
    if (t < 128) {
        float s = 0.f, q = 0.f;
        #pragma unroll
        for (int gg = 0; gg < 8; ++gg) { s += red_s[gg][t]; q += red_q[gg][t]; }
        atomicAdd(&sums[t], s);
        atomicAdd(&sums[128 + t], q);
    }
}

// ---------------- fused BN3 (inline coeffs) + FC(128->6) + log_softmax ----------------

__global__ __launch_bounds__(256) void final_kernel(const float* __restrict__ h,
                                                    const float* __restrict__ sums,
                                                    const float* __restrict__ g3,
                                                    const float* __restrict__ be3,
                                                    const float* __restrict__ fcW,
                                                    const float* __restrict__ fcb,
                                                    float* __restrict__ out) {
    const int t = threadIdx.x, lane = t & 63, wid = t >> 6;
    const int r = blockIdx.x * 4 + wid;
    if (r >= N_NODES) return;
    const float invM = 1.0f / (float)N_NODES;
    float v[6] = {0.f, 0.f, 0.f, 0.f, 0.f, 0.f};
    #pragma unroll
    for (int kk = 0; kk < 2; ++kk) {
        int k = lane + kk * 64;
        float mu = sums[k] * invM;
        float sc = g3[k] * rsqrtf(sums[128 + k] * invM - mu * mu + 1e-5f);
        float sh = be3[k] - mu * sc;
        float x = h[(size_t)r * 128 + k] * sc + sh;
        #pragma unroll
        for (int j = 0; j < 6; ++j) v[j] += x * fcW[k * 6 + j];
    }
    #pragma unroll
    for (int j = 0; j < 6; ++j)
        #pragma unroll
        for (int off = 32; off > 0; off >>= 1) v[j] += __shfl_down(v[j], off);
    if (lane == 0) {
        #pragma unroll
        for (int j = 0; j < 6; ++j) v[j] += fcb[j];
        float m = v[0];
        #pragma unroll
        for (int j = 1; j < 6; ++j) m = fmaxf(m, v[j]);
        float s = 0.f;
        #pragma unroll
        for (int j = 0; j < 6; ++j) s += expf(v[j] - m);
        float l = m + logf(s);
        #pragma unroll
        for (int j = 0; j < 6; ++j) out[r * 6 + j] = v[j] - l;
    }
}

// ---------------- launch ----------------

extern "C" void kernel_launch(void* const* d_in, const int* in_sizes, int n_in,
                              void* d_out, int out_size, void* d_ws, size_t ws_size,
                              hipStream_t stream) {
    (void)in_sizes; (void)n_in; (void)out_size; (void)ws_size;
    const float* x   = (const float*)d_in[0];
    const int*   ei  = (const int*)d_in[1];
    const float* ea  = (const float*)d_in[2];
    const float* W1  = (const float*)d_in[3];
    // b1/b2/b3 (d_in[4],[9],[15]) cancel under training-mode BN
    const float* g1  = (const float*)d_in[5];
    const float* be1 = (const float*)d_in[6];
    const float* W2a = (const float*)d_in[7];
    const float* W2b = (const float*)d_in[8];
    const float* g2  = (const float*)d_in[10];
    const float* be2 = (const float*)d_in[11];
    const float* W3a = (const float*)d_in[12];
    const float* W3b = (const float*)d_in[13];
    const float* W3c = (const float*)d_in[14];
    const float* g3  = (const float*)d_in[16];
    const float* be3 = (const float*)d_in[17];
    const float* fcW = (const float*)d_in[18];
    const float* fcb = (const float*)d_in[19];
    float* out = (float*)d_out;

    const int* src = ei;
    const int* dst = ei + N_EDGES;

    char* w = (char*)d_ws;
    size_t off = 0;
    auto alloc = [&](size_t bytes) -> void* {
        void* p = w + off;
        off += (bytes + 4095) & ~(size_t)4095;
        return p;
    };
    // zeroed region first
    float* deg    = (float*)alloc(N_NODES * 4);
    int*   cnt    = (int*)  alloc(N_NODES * 4);
    int*   fillc  = (int*)  alloc(N_NODES * 4);
    float* sums1  = (float*)alloc(1024 * 4);
    float* sums2  = (float*)alloc(1024 * 4);
    float* sums3  = (float*)alloc(1024 * 4);
    size_t zero_bytes = off;
    float* dis    = (float*)alloc(N_NODES * 4);
    int*   rowptr = (int*)  alloc((N_NODES + 1) * 4);
    int*   csr_s  = (int*)  alloc(N_EDGES * 4);
    float* csr_w  = (float*)alloc(N_EDGES * 4);
    us* B1T = (us*)alloc((size_t)512 * 1536 * 2);
    us* B2T = (us*)alloc((size_t)512 * 1024 * 2);
    us* B3T = (us*)alloc((size_t)384 * 512 * 2);
    // aliased big slots
    us* slotA = (us*)alloc((size_t)MPAD * 1536 * 2);          // A'1/A'2/A'3 (packed)
    float* slotG = (float*)alloc((size_t)N_NODES * 512 * 4);  // G1/G2/G3
    float* slotC = (float*)alloc((size_t)N_NODES * 256 * 4);  // out2 ; then Tc
    float* bufF  = (float*)alloc((size_t)N_NODES * 128 * 4);

    us* A1 = slotA;
    us* A2 = slotA;
    us* A3 = slotA;
    float* G1 = slotG;
    float* G2 = slotG;
    float* G3 = slotG;
    float* out2 = slotC;
    float* bufTc = slotC;    // overwrites out2 after it is consumed

    hipMemsetAsync(d_ws, 0, zero_bytes, stream);

    // graph preprocessing -> dst-CSR with normalized weights
    deg_kernel<<<N_EDGES / 256, 256, 0, stream>>>(src, dst, ea, deg, cnt);
    dis_scan_kernel<<<40, 1024, 0, stream>>>(deg, cnt, dis, rowptr);
    fill_kernel<<<N_EDGES / 256, 256, 0, stream>>>(src, dst, ea, dis, rowptr, fillc,
                                                   csr_s, csr_w);

    // all fp32->bf16 hi/lo packed conversions in one dispatch
    cvt_all_kernel<<<2128, 256, 0, stream>>>(x, A1, W1, B1T, W2a, W2b, B2T,
                                             W3a, W3b, W3c, B3T);

    // ---- layer 1: G1 = x @ W1 (bf16x3) + fused BN stats; BN+ReLU+cvt -> A'2 ----
    mfma_gemm_kernel<<<632, 256, 0, stream>>>(A1, B1T, G1, N_NODES, 768, 512, 8, sums1);
    bn_relu_cvt_kernel<<<dim3(40, 32), 256, 0, stream>>>(G1, sums1, g1, be1, A2, 512);

    // ---- layer 2: G2 = h1 @ [W2a|W2b]; out2 = y0 + P y1; stats; cvt -> A'3 ----
    mfma_gemm_kernel<<<632, 256, 0, stream>>>(A2, B2T, G2, N_NODES, 512, 512, 8, nullptr);
    prop_l2_kernel<<<2500, 256, 0, stream>>>(G2, rowptr, csr_s, csr_w, out2);
    bn_stats256_kernel<<<500, 256, 0, stream>>>(out2, sums2);
    bn_relu_cvt_kernel<<<dim3(40, 16), 256, 0, stream>>>(out2, sums2, g2, be2, A3, 256);

    // ---- layer 3: G3 = h2 @ [W3a|W3b|W3c] = [f0|g1|g2] ----
    mfma_gemm_kernel<<<474, 256, 0, stream>>>(A3, B3T, G3, N_NODES, 256, 384, 6, nullptr);
    // Tc = g1 + 2 P g2 ; out3 = f0 - g2 + P Tc  (+ fused BN stats)
    prop3a_kernel<<<1250, 256, 0, stream>>>(G3, rowptr, csr_s, csr_w, bufTc);
    prop3b_combine_kernel<<<1250, 256, 0, stream>>>(G3, bufTc, rowptr, csr_s, csr_w,
                                                    bufF, sums3);

    // ---- BN3 (inline coeffs) + FC + log_softmax fused ----
    final_kernel<<<2500, 256, 0, stream>>>(bufF, sums3, g3, be3, fcW, fcb, out);
}